// Round 1
// baseline (505.400 us; speedup 1.0000x reference)
//
#include <hip/hip_runtime.h>
#include <float.h>
#include <math.h>

#define B_   8
#define L_   512
#define H_   768
#define W_   5
#define K_   32
#define P_   256
#define EPS_ 1e-5f
#define NEG_ -1e30f

// ---------------- ws layout (floats) ----------------
// Wt : 768*2304            combined weight  [ (w1_s-w1_d) | (w1_e+w1_d) | w1_m ]
// X  : 4096*2304           hidden @ Wt   (A | Bm | C)
// Cc : 8*513*768           cumsum of C part (with leading zero row)
// sc : 8*2560              masked scores
// ts : 256                 top scores
// ti : 256 (int)           top indices
// gl : 256                 gate logits
static const size_t OFF_WT = 0;
static const size_t OFF_X  = OFF_WT + (size_t)768*2304;
static const size_t OFF_CC = OFF_X  + (size_t)4096*2304;
static const size_t OFF_SC = OFF_CC + (size_t)8*513*768;
static const size_t OFF_TS = OFF_SC + (size_t)8*2560;
static const size_t OFF_TI = OFF_TS + 256;
static const size_t OFF_GL = OFF_TI + 256;

// ---------------- kernel 1: build combined weight ----------------
__global__ __launch_bounds__(256) void build_wt_kernel(const float* __restrict__ w1,
                                                       float* __restrict__ Wt) {
    int idx = blockIdx.x * 256 + threadIdx.x;
    if (idx >= 768 * 2304) return;
    int k = idx / 2304, n = idx % 2304;
    float v;
    if (n < 768) {
        v = w1[k * 768 + n] - w1[(2304 + k) * 768 + n];
    } else if (n < 1536) {
        int c = n - 768;
        v = w1[(768 + k) * 768 + c] + w1[(2304 + k) * 768 + c];
    } else {
        int c = n - 1536;
        v = w1[(1536 + k) * 768 + c];
    }
    Wt[idx] = v;
}

// ---------------- kernel 2: fp32 GEMM  (4096x768)@(768x2304) ----------------
__global__ __launch_bounds__(256) void sgemm_kernel(const float* __restrict__ A,
                                                    const float* __restrict__ Bw,
                                                    float* __restrict__ C) {
    __shared__ float As[16][64];
    __shared__ float Bs[16][64];
    int tid = threadIdx.x;
    int bm = blockIdx.x;   // 0..63
    int bn = blockIdx.y;   // 0..35
    int tx = tid & 15, ty = tid >> 4;
    float acc[4][4] = {};

    int arow = tid >> 2;           // 0..63
    int ak   = (tid & 3) * 4;      // 0,4,8,12
    int bk   = tid >> 4;           // 0..15
    int bn4  = (tid & 15) * 4;     // 0..60

    const float* Aptr = A + (size_t)(bm * 64 + arow) * 768 + ak;
    const float* Bptr = Bw + (size_t)bk * 2304 + bn * 64 + bn4;

    for (int k0 = 0; k0 < 768; k0 += 16) {
        float4 av = *(const float4*)(Aptr + k0);
        float4 bv = *(const float4*)(Bptr + (size_t)k0 * 2304);
        As[ak + 0][arow] = av.x;
        As[ak + 1][arow] = av.y;
        As[ak + 2][arow] = av.z;
        As[ak + 3][arow] = av.w;
        *(float4*)&Bs[bk][bn4] = bv;
        __syncthreads();
#pragma unroll
        for (int kk = 0; kk < 16; ++kk) {
            float4 a = *(const float4*)&As[kk][ty * 4];
            float4 b = *(const float4*)&Bs[kk][tx * 4];
            acc[0][0] += a.x * b.x; acc[0][1] += a.x * b.y; acc[0][2] += a.x * b.z; acc[0][3] += a.x * b.w;
            acc[1][0] += a.y * b.x; acc[1][1] += a.y * b.y; acc[1][2] += a.y * b.z; acc[1][3] += a.y * b.w;
            acc[2][0] += a.z * b.x; acc[2][1] += a.z * b.y; acc[2][2] += a.z * b.z; acc[2][3] += a.z * b.w;
            acc[3][0] += a.w * b.x; acc[3][1] += a.w * b.y; acc[3][2] += a.w * b.z; acc[3][3] += a.w * b.w;
        }
        __syncthreads();
    }
#pragma unroll
    for (int i = 0; i < 4; ++i) {
        float* Cp = C + (size_t)(bm * 64 + ty * 4 + i) * 2304 + bn * 64 + tx * 4;
        float4 v = make_float4(acc[i][0], acc[i][1], acc[i][2], acc[i][3]);
        *(float4*)Cp = v;
    }
}

// ---------------- kernel 3: cumsum of C columns over L ----------------
__global__ __launch_bounds__(256) void cumsum_kernel(const float* __restrict__ X,
                                                     float* __restrict__ Cc) {
    int b = blockIdx.x / 3;
    int c = (blockIdx.x % 3) * 256 + threadIdx.x;
    float s = 0.f;
    Cc[(size_t)(b * 513) * 768 + c] = 0.f;
    for (int l = 0; l < 512; ++l) {
        s += X[(size_t)(b * 512 + l) * 2304 + 1536 + c];
        Cc[(size_t)(b * 513 + l + 1) * 768 + c] = s;
    }
}

// ---------------- kernel 4: per-(b,i) span scores ----------------
__global__ __launch_bounds__(256) void score_kernel(const float* __restrict__ X,
                                                    const float* __restrict__ Cc,
                                                    const int* __restrict__ mask,
                                                    const float* __restrict__ b1,
                                                    const float* __restrict__ g1,
                                                    const float* __restrict__ beta1,
                                                    const float* __restrict__ w2,
                                                    const float* __restrict__ b2,
                                                    float* __restrict__ scores) {
    int bi = blockIdx.x;          // 0..4095
    int b = bi >> 9, i = bi & 511;
    int tid = threadIdx.x;
    __shared__ float red[256];
    __shared__ int vmask[5];

    // per-thread columns: tid, tid+256, tid+512
    float a0 = X[(size_t)bi * 2304 + tid];
    float a1 = X[(size_t)bi * 2304 + tid + 256];
    float a2 = X[(size_t)bi * 2304 + tid + 512];
    float ci0 = Cc[(size_t)(b * 513 + i) * 768 + tid];
    float ci1 = Cc[(size_t)(b * 513 + i) * 768 + tid + 256];
    float ci2 = Cc[(size_t)(b * 513 + i) * 768 + tid + 512];

    if (tid < 5) {
        int w = tid;
        bool ok = (i + w) < 512;
        if (ok) {
            for (int t = 0; t <= w; ++t) ok = ok && (mask[b * 512 + i + t] != 0);
        }
        vmask[w] = ok ? 1 : 0;
    }
    __syncthreads();

    for (int w = 0; w < W_; ++w) {
        int j = min(i + w, 511);
        int rowj = b * 512 + j;
        float invw = 1.0f / (float)(w + 1);

        float h0 = a0 + X[(size_t)rowj * 2304 + 768 + tid]
                 + (Cc[(size_t)(b * 513 + j + 1) * 768 + tid] - ci0) * invw + b1[tid];
        float h1 = a1 + X[(size_t)rowj * 2304 + 768 + tid + 256]
                 + (Cc[(size_t)(b * 513 + j + 1) * 768 + tid + 256] - ci1) * invw + b1[tid + 256];
        float h2 = a2 + X[(size_t)rowj * 2304 + 768 + tid + 512]
                 + (Cc[(size_t)(b * 513 + j + 1) * 768 + tid + 512] - ci2) * invw + b1[tid + 512];

        // mean
        red[tid] = h0 + h1 + h2;
        __syncthreads();
        for (int s = 128; s > 0; s >>= 1) { if (tid < s) red[tid] += red[tid + s]; __syncthreads(); }
        float mean = red[0] * (1.f / 768.f);
        __syncthreads();

        // var
        float d0 = h0 - mean, d1 = h1 - mean, d2 = h2 - mean;
        red[tid] = d0 * d0 + d1 * d1 + d2 * d2;
        __syncthreads();
        for (int s = 128; s > 0; s >>= 1) { if (tid < s) red[tid] += red[tid + s]; __syncthreads(); }
        float rstd = rsqrtf(red[0] * (1.f / 768.f) + EPS_);
        __syncthreads();

        // relu(ln)*w2
        float y0 = fmaxf(d0 * rstd * g1[tid] + beta1[tid], 0.f);
        float y1 = fmaxf(d1 * rstd * g1[tid + 256] + beta1[tid + 256], 0.f);
        float y2 = fmaxf(d2 * rstd * g1[tid + 512] + beta1[tid + 512], 0.f);
        red[tid] = y0 * w2[tid] + y1 * w2[tid + 256] + y2 * w2[tid + 512];
        __syncthreads();
        for (int s = 128; s > 0; s >>= 1) { if (tid < s) red[tid] += red[tid + s]; __syncthreads(); }
        if (tid == 0) {
            float sc = red[0] + b2[0];
            scores[b * 2560 + i * 5 + w] = vmask[w] ? sc : NEG_;
        }
        __syncthreads();
    }
}

// ---------------- kernel 5: per-b top-32 (stable, lowest-index ties) ----------------
__global__ __launch_bounds__(256) void topk_kernel(const float* __restrict__ scores,
                                                   float* __restrict__ tops,
                                                   int* __restrict__ topi,
                                                   float* __restrict__ out_masks,
                                                   float* __restrict__ out_scores,
                                                   float* __restrict__ out_spans) {
    int b = blockIdx.x;
    int tid = threadIdx.x;
    __shared__ float sc[2560];
    __shared__ float rv[256];
    __shared__ int ri[256];
    for (int t = tid; t < 2560; t += 256) sc[t] = scores[b * 2560 + t];
    __syncthreads();

    for (int k = 0; k < K_; ++k) {
        float bv = -FLT_MAX; int bidx = 1 << 30;
        for (int t = tid; t < 2560; t += 256) {
            float v = sc[t];
            if (v > bv || (v == bv && t < bidx)) { bv = v; bidx = t; }
        }
        rv[tid] = bv; ri[tid] = bidx;
        __syncthreads();
        for (int s = 128; s > 0; s >>= 1) {
            if (tid < s) {
                float v2 = rv[tid + s]; int i2 = ri[tid + s];
                if (v2 > rv[tid] || (v2 == rv[tid] && i2 < ri[tid])) { rv[tid] = v2; ri[tid] = i2; }
            }
            __syncthreads();
        }
        if (tid == 0) {
            float tv = rv[0]; int tix = ri[0];
            tops[b * 32 + k] = tv;
            topi[b * 32 + k] = tix;
            bool m = tv > (NEG_ * 0.5f);
            out_masks[b * 32 + k] = m ? 1.0f : 0.0f;
            out_scores[b * 32 + k] = m ? tv : -10.0f;
            int tI = tix / 5, tw = tix % 5;
            out_spans[(b * 32 + k) * 2 + 0] = m ? (float)tI : 0.0f;
            out_spans[(b * 32 + k) * 2 + 1] = m ? (float)(tI + tw) : 0.0f;
            sc[tix] = -FLT_MAX;
        }
        __syncthreads();
    }
}

// ---------------- kernel 6: per-(b,k) gate + projection + LN ----------------
__global__ __launch_bounds__(256) void phrase_kernel(const float* __restrict__ hidden,
                                                     const float* __restrict__ tops,
                                                     const int* __restrict__ topi,
                                                     const float* __restrict__ wg1,
                                                     const float* __restrict__ bg1,
                                                     const float* __restrict__ wg2,
                                                     const float* __restrict__ bg2,
                                                     const float* __restrict__ wp,
                                                     const float* __restrict__ bp,
                                                     const float* __restrict__ gout,
                                                     const float* __restrict__ bout,
                                                     float* __restrict__ gate,
                                                     float* __restrict__ out_embeds) {
    int bk = blockIdx.x;            // 0..255
    int b = bk >> 5;
    int tid = threadIdx.x;
    __shared__ float emb[768];
    __shared__ float red[256];
    __shared__ float bc[2];

    int idx = topi[bk];
    bool valid = tops[bk] > (NEG_ * 0.5f);
    int tI = idx / 5, tw = idx % 5;
    int jend = min(tI + tw, L_ - 1);
    float inv = 1.0f / (float)(tw + 1);

    for (int c = tid; c < 768; c += 256) {
        float s = 0.f;
        if (valid) {
            for (int l = tI; l <= jend; ++l) s += hidden[(size_t)(b * 512 + l) * 768 + c];
            s *= inv;
        }
        emb[c] = s;
    }
    __syncthreads();

    // gate logits
    float gl_part = 0.f;
    for (int n = tid; n < 384; n += 256) {
        float s = bg1[n];
        for (int c = 0; c < 768; ++c) s += emb[c] * wg1[(size_t)c * 384 + n];
        gl_part += tanhf(s) * wg2[n];
    }
    red[tid] = gl_part;
    __syncthreads();
    for (int s = 128; s > 0; s >>= 1) { if (tid < s) red[tid] += red[tid + s]; __syncthreads(); }
    if (tid == 0) gate[bk] = valid ? (red[0] + bg2[0]) : -1e9f;

    // projection (256 outputs, one per thread)
    float p = bp[tid];
    for (int c = 0; c < 768; ++c) p += emb[c] * wp[(size_t)c * 256 + tid];
    __syncthreads();

    // LN over 256
    red[tid] = p;
    __syncthreads();
    for (int s = 128; s > 0; s >>= 1) { if (tid < s) red[tid] += red[tid + s]; __syncthreads(); }
    if (tid == 0) bc[0] = red[0] * (1.f / 256.f);
    __syncthreads();
    float m = bc[0];
    float d = p - m;
    red[tid] = d * d;
    __syncthreads();
    for (int s = 128; s > 0; s >>= 1) { if (tid < s) red[tid] += red[tid + s]; __syncthreads(); }
    if (tid == 0) bc[1] = red[0] * (1.f / 256.f);
    __syncthreads();
    float rstd = rsqrtf(bc[1] + EPS_);
    out_embeds[(size_t)bk * 256 + tid] = d * rstd * gout[tid] + bout[tid];
}

// ---------------- kernel 7: softmax over K per b ----------------
__global__ void attn_kernel(const float* __restrict__ gate, float* __restrict__ out_attn) {
    int b = threadIdx.x;
    if (b < 8) {
        float mx = -FLT_MAX;
        for (int k = 0; k < 32; ++k) mx = fmaxf(mx, gate[b * 32 + k]);
        float e[32];
        float s = 0.f;
        for (int k = 0; k < 32; ++k) { e[k] = expf(gate[b * 32 + k] - mx); s += e[k]; }
        float inv = 1.f / s;
        for (int k = 0; k < 32; ++k) out_attn[b * 32 + k] = e[k] * inv;
    }
}

extern "C" void kernel_launch(void* const* d_in, const int* in_sizes, int n_in,
                              void* d_out, int out_size, void* d_ws, size_t ws_size,
                              hipStream_t stream) {
    const float* hidden = (const float*)d_in[0];
    const int*   amask  = (const int*)d_in[1];
    const float* w1     = (const float*)d_in[2];
    const float* b1     = (const float*)d_in[3];
    const float* g1     = (const float*)d_in[4];
    const float* beta1  = (const float*)d_in[5];
    const float* w2     = (const float*)d_in[6];
    const float* b2     = (const float*)d_in[7];
    const float* wp     = (const float*)d_in[8];
    const float* bp     = (const float*)d_in[9];
    const float* wg1    = (const float*)d_in[10];
    const float* bg1    = (const float*)d_in[11];
    const float* wg2    = (const float*)d_in[12];
    const float* bg2    = (const float*)d_in[13];
    const float* gout   = (const float*)d_in[14];
    const float* bout   = (const float*)d_in[15];

    float* ws = (float*)d_ws;
    float* Wt = ws + OFF_WT;
    float* X  = ws + OFF_X;
    float* Cc = ws + OFF_CC;
    float* sc = ws + OFF_SC;
    float* ts = ws + OFF_TS;
    int*   ti = (int*)(ws + OFF_TI);
    float* gl = ws + OFF_GL;

    float* out = (float*)d_out;
    float* out_embeds = out;                   // 8*32*256 = 65536
    float* out_masks  = out + 65536;           // 256
    float* out_attn   = out + 65792;           // 256
    float* out_scores = out + 66048;           // 256
    float* out_spans  = out + 66304;           // 512

    build_wt_kernel<<<(768 * 2304 + 255) / 256, 256, 0, stream>>>(w1, Wt);
    sgemm_kernel<<<dim3(64, 36), 256, 0, stream>>>(hidden, Wt, X);
    cumsum_kernel<<<24, 256, 0, stream>>>(X, Cc);
    score_kernel<<<4096, 256, 0, stream>>>(X, Cc, amask, b1, g1, beta1, w2, b2, sc);
    topk_kernel<<<8, 256, 0, stream>>>(sc, ts, ti, out_masks, out_scores, out_spans);
    phrase_kernel<<<256, 256, 0, stream>>>(hidden, ts, ti, wg1, bg1, wg2, bg2,
                                           wp, bp, gout, bout, gl, out_embeds);
    attn_kernel<<<1, 64, 0, stream>>>(gl, out_attn);
}

// Round 2
// 437.295 us; speedup vs baseline: 1.1557x; 1.1557x over previous
//
#include <hip/hip_runtime.h>
#include <float.h>
#include <math.h>

#define B_   8
#define L_   512
#define H_   768
#define W_   5
#define K_   32
#define P_   256
#define EPS_ 1e-5f
#define NEG_ -1e30f

// ---------------- ws layout (floats) ----------------
static const size_t OFF_WT = 0;                               // 768*2304 combined weight
static const size_t OFF_X  = OFF_WT + (size_t)768*2304;       // 4096*2304  hidden @ Wt (A|B|C)
static const size_t OFF_SC = OFF_X  + (size_t)4096*2304;      // 8*2560 scores
static const size_t OFF_TS = OFF_SC + (size_t)8*2560;         // 256 top scores
static const size_t OFF_TI = OFF_TS + 256;                    // 256 top idx (int)
static const size_t OFF_GL = OFF_TI + 256;                    // 256 gate logits

// ---------------- kernel 1: build combined weight ----------------
// Wt[k][n] (768 x 2304): n<768: w1_s - w1_d ; 768..1535: w1_e + w1_d ; 1536..: w1_m
__global__ __launch_bounds__(256) void build_wt_kernel(const float* __restrict__ w1,
                                                       float* __restrict__ Wt) {
    int idx = blockIdx.x * 256 + threadIdx.x;
    if (idx >= 768 * 2304) return;
    int k = idx / 2304, n = idx % 2304;
    float v;
    if (n < 768) {
        v = w1[k * 768 + n] - w1[(2304 + k) * 768 + n];
    } else if (n < 1536) {
        int c = n - 768;
        v = w1[(768 + k) * 768 + c] + w1[(2304 + k) * 768 + c];
    } else {
        int c = n - 1536;
        v = w1[(1536 + k) * 768 + c];
    }
    Wt[idx] = v;
}

// ---------------- kernel 2: fp32 GEMM  (4096x768)@(768x2304), 128x128 tile ----------------
__global__ __launch_bounds__(256) void sgemm_kernel(const float* __restrict__ A,
                                                    const float* __restrict__ Bw,
                                                    float* __restrict__ C) {
    __shared__ float As[16][128];
    __shared__ float Bs[16][128];
    int tid = threadIdx.x;
    int bm = blockIdx.x;   // 0..31
    int bn = blockIdx.y;   // 0..17
    int tx = tid & 15;     // col group (8 cols)
    int ty = tid >> 4;     // row group (8 rows)
    float acc[8][8] = {};

    // A staging: thread -> row ar (0..127), k-offset akq (0 or 8); 2 float4 loads,
    // 8 scalar transposed stores: bank = ar%32, 2 lanes/bank -> free.
    int ar  = tid >> 1;
    int akq = (tid & 1) * 8;
    const float* Ap = A + (size_t)(bm * 128 + ar) * 768 + akq;

    // B staging: thread -> k-row bkk (0..15), col bc (0..60); float4 stores at bc, bc+64.
    int bkk = tid >> 4;
    int bc  = (tid & 15) * 4;
    const float* Bp = Bw + (size_t)bkk * 2304 + bn * 128 + bc;

    for (int k0 = 0; k0 < 768; k0 += 16) {
        float4 av0 = *(const float4*)(Ap + k0);
        float4 av1 = *(const float4*)(Ap + k0 + 4);
        float4 bv0 = *(const float4*)(Bp + (size_t)k0 * 2304);
        float4 bv1 = *(const float4*)(Bp + (size_t)k0 * 2304 + 64);
        __syncthreads();
        As[akq + 0][ar] = av0.x;
        As[akq + 1][ar] = av0.y;
        As[akq + 2][ar] = av0.z;
        As[akq + 3][ar] = av0.w;
        As[akq + 4][ar] = av1.x;
        As[akq + 5][ar] = av1.y;
        As[akq + 6][ar] = av1.z;
        As[akq + 7][ar] = av1.w;
        *(float4*)&Bs[bkk][bc]      = bv0;
        *(float4*)&Bs[bkk][bc + 64] = bv1;
        __syncthreads();
#pragma unroll
        for (int kk = 0; kk < 16; ++kk) {
            float4 a0 = *(const float4*)&As[kk][ty * 8];
            float4 a1 = *(const float4*)&As[kk][ty * 8 + 4];
            float4 b0 = *(const float4*)&Bs[kk][tx * 8];
            float4 b1v = *(const float4*)&Bs[kk][tx * 8 + 4];
            float aa[8] = {a0.x, a0.y, a0.z, a0.w, a1.x, a1.y, a1.z, a1.w};
            float bb[8] = {b0.x, b0.y, b0.z, b0.w, b1v.x, b1v.y, b1v.z, b1v.w};
#pragma unroll
            for (int i = 0; i < 8; ++i)
#pragma unroll
                for (int j = 0; j < 8; ++j)
                    acc[i][j] += aa[i] * bb[j];
        }
    }
#pragma unroll
    for (int i = 0; i < 8; ++i) {
        float* Cp = C + (size_t)(bm * 128 + ty * 8 + i) * 2304 + bn * 128 + tx * 8;
        float4 v0 = make_float4(acc[i][0], acc[i][1], acc[i][2], acc[i][3]);
        float4 v1 = make_float4(acc[i][4], acc[i][5], acc[i][6], acc[i][7]);
        *(float4*)Cp = v0;
        *(float4*)(Cp + 4) = v1;
    }
}

// ---------------- kernel 3: per-(b,i) span scores, one wave per (b,i) ----------------
__global__ __launch_bounds__(256) void score_kernel(const float* __restrict__ X,
                                                    const int* __restrict__ mask,
                                                    const float* __restrict__ b1,
                                                    const float* __restrict__ g1,
                                                    const float* __restrict__ beta1,
                                                    const float* __restrict__ w2,
                                                    const float* __restrict__ b2,
                                                    float* __restrict__ scores) {
    int wave = threadIdx.x >> 6;
    int lane = threadIdx.x & 63;
    int bi = blockIdx.x * 4 + wave;    // 0..4095
    int b = bi >> 9, i = bi & 511;

    float a[12], b1c[12], g1c[12], btc[12], w2c[12], ss[12], e[12];
    const float* Xrow = X + (size_t)bi * 2304;
#pragma unroll
    for (int q = 0; q < 12; ++q) {
        int c = lane + q * 64;
        a[q]   = Xrow[c];
        b1c[q] = b1[c];
        g1c[q] = g1[c];
        btc[q] = beta1[c];
        w2c[q] = w2[c];
        ss[q]  = 0.f;
    }
    float bias2 = b2[0];
    int jcur = i - 1;
    float sc_loc[W_];

    for (int w = 0; w < W_; ++w) {
        int j = min(i + w, 511);
        const float* Xj = X + (size_t)(b * 512 + j) * 2304;
        if (j > jcur) {
#pragma unroll
            for (int q = 0; q < 12; ++q) {
                int c = lane + q * 64;
                ss[q] += Xj[1536 + c];
                e[q]   = Xj[768 + c];
            }
            jcur = j;
        }
        float invw = 1.0f / (float)(w + 1);
        float h[12];
        float psum = 0.f;
#pragma unroll
        for (int q = 0; q < 12; ++q) {
            h[q] = a[q] + e[q] + ss[q] * invw + b1c[q];
            psum += h[q];
        }
#pragma unroll
        for (int m = 1; m < 64; m <<= 1) psum += __shfl_xor(psum, m, 64);
        float mean = psum * (1.f / 768.f);

        float pv = 0.f;
#pragma unroll
        for (int q = 0; q < 12; ++q) {
            float d = h[q] - mean;
            pv += d * d;
        }
#pragma unroll
        for (int m = 1; m < 64; m <<= 1) pv += __shfl_xor(pv, m, 64);
        float rstd = rsqrtf(pv * (1.f / 768.f) + EPS_);

        float pd = 0.f;
#pragma unroll
        for (int q = 0; q < 12; ++q) {
            float d = h[q] - mean;
            float y = fmaxf(d * rstd * g1c[q] + btc[q], 0.f);
            pd += y * w2c[q];
        }
#pragma unroll
        for (int m = 1; m < 64; m <<= 1) pd += __shfl_xor(pd, m, 64);
        sc_loc[w] = pd + bias2;
    }

    if (lane < W_) {
        int w = lane;
        bool ok = (i + w) < 512;
        if (ok) {
            for (int t = 0; t <= w; ++t) ok = ok && (mask[b * 512 + i + t] != 0);
        }
        scores[b * 2560 + i * 5 + w] = ok ? sc_loc[w] : NEG_;
    }
}

// ---------------- kernel 4: per-b top-32 (stable, lowest-index ties) ----------------
__global__ __launch_bounds__(256) void topk_kernel(const float* __restrict__ scores,
                                                   float* __restrict__ tops,
                                                   int* __restrict__ topi,
                                                   float* __restrict__ out_masks,
                                                   float* __restrict__ out_scores,
                                                   float* __restrict__ out_spans) {
    int b = blockIdx.x;
    int tid = threadIdx.x;
    int lane = tid & 63;
    int wv = tid >> 6;
    __shared__ float sc[2560];
    __shared__ float wv_v[4];
    __shared__ int   wv_i[4];
    for (int t = tid; t < 2560; t += 256) sc[t] = scores[b * 2560 + t];
    __syncthreads();

    for (int k = 0; k < K_; ++k) {
        float bv = -FLT_MAX; int bix = 1 << 30;
        for (int t = tid; t < 2560; t += 256) {
            float v = sc[t];
            if (v > bv || (v == bv && t < bix)) { bv = v; bix = t; }
        }
#pragma unroll
        for (int m = 1; m < 64; m <<= 1) {
            float v2 = __shfl_xor(bv, m, 64);
            int   i2 = __shfl_xor(bix, m, 64);
            if (v2 > bv || (v2 == bv && i2 < bix)) { bv = v2; bix = i2; }
        }
        if (lane == 0) { wv_v[wv] = bv; wv_i[wv] = bix; }
        __syncthreads();
        if (tid == 0) {
            float tv = wv_v[0]; int tix = wv_i[0];
            for (int q = 1; q < 4; ++q) {
                if (wv_v[q] > tv || (wv_v[q] == tv && wv_i[q] < tix)) { tv = wv_v[q]; tix = wv_i[q]; }
            }
            tops[b * 32 + k] = tv;
            topi[b * 32 + k] = tix;
            bool m = tv > (NEG_ * 0.5f);
            out_masks[b * 32 + k] = m ? 1.0f : 0.0f;
            out_scores[b * 32 + k] = m ? tv : -10.0f;
            int tI = tix / 5, tw = tix % 5;
            out_spans[(b * 32 + k) * 2 + 0] = m ? (float)tI : 0.0f;
            out_spans[(b * 32 + k) * 2 + 1] = m ? (float)(tI + tw) : 0.0f;
            sc[tix] = -FLT_MAX;
        }
        __syncthreads();
    }
}

// ---------------- kernel 5: per-(b,k) gate + projection + LN ----------------
__global__ __launch_bounds__(256) void phrase_kernel(const float* __restrict__ hidden,
                                                     const float* __restrict__ tops,
                                                     const int* __restrict__ topi,
                                                     const float* __restrict__ wg1,
                                                     const float* __restrict__ bg1,
                                                     const float* __restrict__ wg2,
                                                     const float* __restrict__ bg2,
                                                     const float* __restrict__ wp,
                                                     const float* __restrict__ bp,
                                                     const float* __restrict__ gout,
                                                     const float* __restrict__ bout,
                                                     float* __restrict__ gate,
                                                     float* __restrict__ out_embeds) {
    int bk = blockIdx.x;            // 0..255
    int b = bk >> 5;
    int tid = threadIdx.x;
    __shared__ float emb[768];
    __shared__ float red[256];
    __shared__ float bc2[2];

    int idx = topi[bk];
    bool valid = tops[bk] > (NEG_ * 0.5f);
    int tI = idx / 5, tw = idx % 5;
    int jend = min(tI + tw, L_ - 1);
    float inv = 1.0f / (float)(tw + 1);

    for (int c = tid; c < 768; c += 256) {
        float s = 0.f;
        if (valid) {
            for (int l = tI; l <= jend; ++l) s += hidden[(size_t)(b * 512 + l) * 768 + c];
            s *= inv;
        }
        emb[c] = s;
    }
    __syncthreads();

    // gate logits
    float gl_part = 0.f;
    for (int n = tid; n < 384; n += 256) {
        float s = bg1[n];
        for (int c = 0; c < 768; ++c) s += emb[c] * wg1[(size_t)c * 384 + n];
        gl_part += tanhf(s) * wg2[n];
    }
    red[tid] = gl_part;
    __syncthreads();
    for (int s = 128; s > 0; s >>= 1) { if (tid < s) red[tid] += red[tid + s]; __syncthreads(); }
    if (tid == 0) gate[bk] = valid ? (red[0] + bg2[0]) : -1e9f;

    // projection (256 outputs, one per thread)
    float p = bp[tid];
    for (int c = 0; c < 768; ++c) p += emb[c] * wp[(size_t)c * 256 + tid];
    __syncthreads();

    // LN over 256
    red[tid] = p;
    __syncthreads();
    for (int s = 128; s > 0; s >>= 1) { if (tid < s) red[tid] += red[tid + s]; __syncthreads(); }
    if (tid == 0) bc2[0] = red[0] * (1.f / 256.f);
    __syncthreads();
    float m = bc2[0];
    float d = p - m;
    red[tid] = d * d;
    __syncthreads();
    for (int s = 128; s > 0; s >>= 1) { if (tid < s) red[tid] += red[tid + s]; __syncthreads(); }
    if (tid == 0) bc2[1] = red[0] * (1.f / 256.f);
    __syncthreads();
    float rstd = rsqrtf(bc2[1] + EPS_);
    out_embeds[(size_t)bk * 256 + tid] = d * rstd * gout[tid] + bout[tid];
}

// ---------------- kernel 6: softmax over K per b ----------------
__global__ void attn_kernel(const float* __restrict__ gate, float* __restrict__ out_attn) {
    int b = threadIdx.x;
    if (b < 8) {
        float mx = -FLT_MAX;
        for (int k = 0; k < 32; ++k) mx = fmaxf(mx, gate[b * 32 + k]);
        float e[32];
        float s = 0.f;
        for (int k = 0; k < 32; ++k) { e[k] = expf(gate[b * 32 + k] - mx); s += e[k]; }
        float inv = 1.f / s;
        for (int k = 0; k < 32; ++k) out_attn[b * 32 + k] = e[k] * inv;
    }
}

extern "C" void kernel_launch(void* const* d_in, const int* in_sizes, int n_in,
                              void* d_out, int out_size, void* d_ws, size_t ws_size,
                              hipStream_t stream) {
    const float* hidden = (const float*)d_in[0];
    const int*   amask  = (const int*)d_in[1];
    const float* w1     = (const float*)d_in[2];
    const float* b1     = (const float*)d_in[3];
    const float* g1     = (const float*)d_in[4];
    const float* beta1  = (const float*)d_in[5];
    const float* w2     = (const float*)d_in[6];
    const float* b2     = (const float*)d_in[7];
    const float* wp     = (const float*)d_in[8];
    const float* bp     = (const float*)d_in[9];
    const float* wg1    = (const float*)d_in[10];
    const float* bg1    = (const float*)d_in[11];
    const float* wg2    = (const float*)d_in[12];
    const float* bg2    = (const float*)d_in[13];
    const float* gout   = (const float*)d_in[14];
    const float* bout   = (const float*)d_in[15];

    float* ws = (float*)d_ws;
    float* Wt = ws + OFF_WT;
    float* X  = ws + OFF_X;
    float* sc = ws + OFF_SC;
    float* ts = ws + OFF_TS;
    int*   ti = (int*)(ws + OFF_TI);
    float* gl = ws + OFF_GL;

    float* out = (float*)d_out;
    float* out_embeds = out;                   // 8*32*256 = 65536
    float* out_masks  = out + 65536;           // 256
    float* out_attn   = out + 65792;           // 256
    float* out_scores = out + 66048;           // 256
    float* out_spans  = out + 66304;           // 512

    build_wt_kernel<<<(768 * 2304 + 255) / 256, 256, 0, stream>>>(w1, Wt);
    sgemm_kernel<<<dim3(32, 18), 256, 0, stream>>>(hidden, Wt, X);
    score_kernel<<<1024, 256, 0, stream>>>(X, amask, b1, g1, beta1, w2, b2, sc);
    topk_kernel<<<8, 256, 0, stream>>>(sc, ts, ti, out_masks, out_scores, out_spans);
    phrase_kernel<<<256, 256, 0, stream>>>(hidden, ts, ti, wg1, bg1, wg2, bg2,
                                           wp, bp, gout, bout, gl, out_embeds);
    attn_kernel<<<1, 64, 0, stream>>>(gl, out_attn);
}

// Round 3
// 313.828 us; speedup vs baseline: 1.6104x; 1.3934x over previous
//
#include <hip/hip_runtime.h>
#include <float.h>
#include <math.h>

#define B_   8
#define L_   512
#define H_   768
#define W_   5
#define K_   32
#define P_   256
#define EPS_ 1e-5f
#define NEG_ -1e30f

typedef _Float16 half8 __attribute__((ext_vector_type(8)));
typedef _Float16 half4v __attribute__((ext_vector_type(4)));
typedef float floatx4 __attribute__((ext_vector_type(4)));

// ---------------- ws layout (float units) ----------------
static const size_t OFF_X  = 0;                   // 4096*2304 f32
static const size_t OFF_AH = 9437184;             // 4096*768 f16 (hi)  = 1572864 float units
static const size_t OFF_AL = 11010048;            // 4096*768 f16 (lo)
static const size_t OFF_BH = 12582912;            // 2304*768 f16 (WtT hi) = 884736 float units
static const size_t OFF_BL = 13467648;            // 2304*768 f16 (WtT lo)
static const size_t OFF_SC = 14352384;            // 8*2560 scores
static const size_t OFF_TS = 14372864;            // 256
static const size_t OFF_TI = 14373120;            // 256 (int)
static const size_t OFF_GL = 14373376;            // 256

#define A_SCALE 8.0f
#define B_SCALE 64.0f
#define INV_SCALE (1.0f / 512.0f)

// ---------------- kernel 1: split hidden -> f16 hi/lo (scaled x8) ----------------
__global__ __launch_bounds__(256) void split_hidden_kernel(const float* __restrict__ hid,
                                                           _Float16* __restrict__ ah,
                                                           _Float16* __restrict__ al) {
    int idx = (blockIdx.x * 256 + threadIdx.x) * 4;   // total 3,145,728 elems -> 3072 blocks
    float4 x = *(const float4*)(hid + idx);
    float xs[4] = {x.x * A_SCALE, x.y * A_SCALE, x.z * A_SCALE, x.w * A_SCALE};
    half4v h, l;
#pragma unroll
    for (int i = 0; i < 4; ++i) {
        _Float16 hi = (_Float16)xs[i];
        h[i] = hi;
        l[i] = (_Float16)(xs[i] - (float)hi);
    }
    *(half4v*)(ah + idx) = h;
    *(half4v*)(al + idx) = l;
}

// ---------------- kernel 2: build transposed combined weight, f16 hi/lo (scaled x64) ----
// WtT[n][k], n in [0,2304), k in [0,768):
//   n<768   : w1_s - w1_d ; 768..1535 : w1_e + w1_d ; >=1536 : w1_m
__global__ __launch_bounds__(256) void build_wt_kernel(const float* __restrict__ w1,
                                                       _Float16* __restrict__ bh,
                                                       _Float16* __restrict__ bl) {
    __shared__ float ld[64][65];
    int n0 = blockIdx.x * 64;    // 36 blocks
    int k0 = blockIdx.y * 64;    // 12 blocks
    int t = threadIdx.x;
    int rsel = n0 / 768;         // block-uniform (768 % 64 == 0)
    int c0 = n0 - rsel * 768;
#pragma unroll 4
    for (int r = 0; r < 16; ++r) {
        int idx = r * 256 + t;
        int kk = idx >> 6, nn = idx & 63;
        int k = k0 + kk, c = c0 + nn;
        float v;
        if (rsel == 0)      v = w1[(size_t)k * 768 + c] - w1[(size_t)(2304 + k) * 768 + c];
        else if (rsel == 1) v = w1[(size_t)(768 + k) * 768 + c] + w1[(size_t)(2304 + k) * 768 + c];
        else                v = w1[(size_t)(1536 + k) * 768 + c];
        ld[kk][nn] = v * B_SCALE;
    }
    __syncthreads();
#pragma unroll 4
    for (int r = 0; r < 16; ++r) {
        int idx = r * 256 + t;
        int nn = idx >> 6, kk = idx & 63;
        float v = ld[kk][nn];
        _Float16 h = (_Float16)v;
        _Float16 lo = (_Float16)(v - (float)h);
        size_t o = (size_t)(n0 + nn) * 768 + k0 + kk;
        bh[o] = h;
        bl[o] = lo;
    }
}

// ---------------- kernel 3: split-f16 MFMA GEMM ----------------
// X[4096][2304] = (Ah+Al)[4096][768] @ (Bh+Bl)^T[768][2304], 3 products, fp32 acc.
// 128x128 tile, BK=32, 4 waves; wave w stages one of {Ah,Al,Bh,Bl} via global_load_lds(16B).
// LDS tile layout [row][kgroup-swizzled]: slot (r, q) holds k-group q ^ ((r>>1)&3),
// making both staging (lane-sequential) and frag ds_read_b128 (2 lanes/bank) conflict-free.
typedef const __attribute__((address_space(1))) void* gas_ptr;
typedef __attribute__((address_space(3))) void* las_ptr;
__device__ __forceinline__ void async_ld16(const _Float16* g, _Float16* l) {
    __builtin_amdgcn_global_load_lds((gas_ptr)g, (las_ptr)l, 16, 0, 0);
}

__global__ __launch_bounds__(256) void mfma_gemm_kernel(const _Float16* __restrict__ Ah,
                                                        const _Float16* __restrict__ Al,
                                                        const _Float16* __restrict__ Bh,
                                                        const _Float16* __restrict__ Bl,
                                                        float* __restrict__ C) {
    __shared__ _Float16 sAh[128 * 32];
    __shared__ _Float16 sAl[128 * 32];
    __shared__ _Float16 sBh[128 * 32];
    __shared__ _Float16 sBl[128 * 32];
    int tid = threadIdx.x;
    int lane = tid & 63;
    int wave = tid >> 6;
    int m0 = blockIdx.x * 128, n0 = blockIdx.y * 128;

    // staging role
    const _Float16* src = (wave == 0) ? Ah : (wave == 1) ? Al : (wave == 2) ? Bh : Bl;
    _Float16* dst = (wave == 0) ? sAh : (wave == 1) ? sAl : (wave == 2) ? sBh : sBl;
    int row0 = (wave < 2) ? m0 : n0;
    int qg = (lane & 3) ^ ((lane >> 3) & 3);            // swizzled source k-group
    const _Float16* gp = src + (size_t)(row0 + (lane >> 2)) * 768 + qg * 8;

    // compute role: wave -> 64x64 quadrant
    int wr = wave >> 1, wc = wave & 1;
    int off_lane = (lane & 15) * 64 + (((lane >> 4) ^ ((lane >> 1) & 3)) * 16);  // bytes
    const char* pAh = (const char*)sAh + wr * 4096 + off_lane;
    const char* pAl = (const char*)sAl + wr * 4096 + off_lane;
    const char* pBh = (const char*)sBh + wc * 4096 + off_lane;
    const char* pBl = (const char*)sBl + wc * 4096 + off_lane;

    floatx4 acc[4][4];
#pragma unroll
    for (int i = 0; i < 4; ++i)
#pragma unroll
        for (int j = 0; j < 4; ++j)
            acc[i][j] = (floatx4){0.f, 0.f, 0.f, 0.f};

    for (int k0 = 0; k0 < 768; k0 += 32) {
        __syncthreads();   // previous iteration's frag reads complete
#pragma unroll
        for (int c = 0; c < 8; ++c)
            async_ld16(gp + k0 + (size_t)c * 16 * 768, dst + c * 512);
        __syncthreads();   // compiler drains vmcnt(0) before barrier -> LDS ready

        half8 a_h[4], a_l[4], b_h[4], b_l[4];
#pragma unroll
        for (int i = 0; i < 4; ++i) {
            a_h[i] = *(const half8*)(pAh + i * 1024);
            a_l[i] = *(const half8*)(pAl + i * 1024);
            b_h[i] = *(const half8*)(pBh + i * 1024);
            b_l[i] = *(const half8*)(pBl + i * 1024);
        }
#pragma unroll
        for (int i = 0; i < 4; ++i)
#pragma unroll
            for (int j = 0; j < 4; ++j) {
                acc[i][j] = __builtin_amdgcn_mfma_f32_16x16x32_f16(a_h[i], b_h[j], acc[i][j], 0, 0, 0);
                acc[i][j] = __builtin_amdgcn_mfma_f32_16x16x32_f16(a_h[i], b_l[j], acc[i][j], 0, 0, 0);
                acc[i][j] = __builtin_amdgcn_mfma_f32_16x16x32_f16(a_l[i], b_h[j], acc[i][j], 0, 0, 0);
            }
    }

    int colc = lane & 15, quad = lane >> 4;
#pragma unroll
    for (int i = 0; i < 4; ++i) {
#pragma unroll
        for (int r = 0; r < 4; ++r) {
            int row = m0 + wr * 64 + i * 16 + quad * 4 + r;
            float* Cp = C + (size_t)row * 2304 + n0 + wc * 64 + colc;
#pragma unroll
            for (int j = 0; j < 4; ++j)
                Cp[j * 16] = acc[i][j][r] * INV_SCALE;
        }
    }
}

// ---------------- kernel 4: per-(b,i) span scores, one wave per (b,i) ----------------
__global__ __launch_bounds__(256) void score_kernel(const float* __restrict__ X,
                                                    const int* __restrict__ mask,
                                                    const float* __restrict__ b1,
                                                    const float* __restrict__ g1,
                                                    const float* __restrict__ beta1,
                                                    const float* __restrict__ w2,
                                                    const float* __restrict__ b2,
                                                    float* __restrict__ scores) {
    int wave = threadIdx.x >> 6;
    int lane = threadIdx.x & 63;
    int bi = blockIdx.x * 4 + wave;    // 0..4095
    int b = bi >> 9, i = bi & 511;

    float a[12], b1c[12], g1c[12], btc[12], w2c[12], ss[12], e[12];
    const float* Xrow = X + (size_t)bi * 2304;
#pragma unroll
    for (int q = 0; q < 12; ++q) {
        int c = lane + q * 64;
        a[q]   = Xrow[c];
        b1c[q] = b1[c];
        g1c[q] = g1[c];
        btc[q] = beta1[c];
        w2c[q] = w2[c];
        ss[q]  = 0.f;
    }
    float bias2 = b2[0];
    int jcur = i - 1;
    float sc_loc[W_];

    for (int w = 0; w < W_; ++w) {
        int j = min(i + w, 511);
        const float* Xj = X + (size_t)(b * 512 + j) * 2304;
        if (j > jcur) {
#pragma unroll
            for (int q = 0; q < 12; ++q) {
                int c = lane + q * 64;
                ss[q] += Xj[1536 + c];
                e[q]   = Xj[768 + c];
            }
            jcur = j;
        }
        float invw = 1.0f / (float)(w + 1);
        float h[12];
        float psum = 0.f;
#pragma unroll
        for (int q = 0; q < 12; ++q) {
            h[q] = a[q] + e[q] + ss[q] * invw + b1c[q];
            psum += h[q];
        }
#pragma unroll
        for (int m = 1; m < 64; m <<= 1) psum += __shfl_xor(psum, m, 64);
        float mean = psum * (1.f / 768.f);

        float pv = 0.f;
#pragma unroll
        for (int q = 0; q < 12; ++q) {
            float d = h[q] - mean;
            pv += d * d;
        }
#pragma unroll
        for (int m = 1; m < 64; m <<= 1) pv += __shfl_xor(pv, m, 64);
        float rstd = rsqrtf(pv * (1.f / 768.f) + EPS_);

        float pd = 0.f;
#pragma unroll
        for (int q = 0; q < 12; ++q) {
            float d = h[q] - mean;
            float y = fmaxf(d * rstd * g1c[q] + btc[q], 0.f);
            pd += y * w2c[q];
        }
#pragma unroll
        for (int m = 1; m < 64; m <<= 1) pd += __shfl_xor(pd, m, 64);
        sc_loc[w] = pd + bias2;
    }

    if (lane < W_) {
        int w = lane;
        bool ok = (i + w) < 512;
        if (ok) {
            for (int t = 0; t <= w; ++t) ok = ok && (mask[b * 512 + i + t] != 0);
        }
        scores[b * 2560 + i * 5 + w] = ok ? sc_loc[w] : NEG_;
    }
}

// ---------------- kernel 5: per-b top-32 (stable, lowest-index ties) ----------------
__global__ __launch_bounds__(256) void topk_kernel(const float* __restrict__ scores,
                                                   float* __restrict__ tops,
                                                   int* __restrict__ topi,
                                                   float* __restrict__ out_masks,
                                                   float* __restrict__ out_scores,
                                                   float* __restrict__ out_spans) {
    int b = blockIdx.x;
    int tid = threadIdx.x;
    int lane = tid & 63;
    int wv = tid >> 6;
    __shared__ float sc[2560];
    __shared__ float wv_v[4];
    __shared__ int   wv_i[4];
    for (int t = tid; t < 2560; t += 256) sc[t] = scores[b * 2560 + t];
    __syncthreads();

    for (int k = 0; k < K_; ++k) {
        float bv = -FLT_MAX; int bix = 1 << 30;
        for (int t = tid; t < 2560; t += 256) {
            float v = sc[t];
            if (v > bv || (v == bv && t < bix)) { bv = v; bix = t; }
        }
#pragma unroll
        for (int m = 1; m < 64; m <<= 1) {
            float v2 = __shfl_xor(bv, m, 64);
            int   i2 = __shfl_xor(bix, m, 64);
            if (v2 > bv || (v2 == bv && i2 < bix)) { bv = v2; bix = i2; }
        }
        if (lane == 0) { wv_v[wv] = bv; wv_i[wv] = bix; }
        __syncthreads();
        if (tid == 0) {
            float tv = wv_v[0]; int tix = wv_i[0];
            for (int q = 1; q < 4; ++q) {
                if (wv_v[q] > tv || (wv_v[q] == tv && wv_i[q] < tix)) { tv = wv_v[q]; tix = wv_i[q]; }
            }
            tops[b * 32 + k] = tv;
            topi[b * 32 + k] = tix;
            bool m = tv > (NEG_ * 0.5f);
            out_masks[b * 32 + k] = m ? 1.0f : 0.0f;
            out_scores[b * 32 + k] = m ? tv : -10.0f;
            int tI = tix / 5, tw = tix % 5;
            out_spans[(b * 32 + k) * 2 + 0] = m ? (float)tI : 0.0f;
            out_spans[(b * 32 + k) * 2 + 1] = m ? (float)(tI + tw) : 0.0f;
            sc[tix] = -FLT_MAX;
        }
        __syncthreads();
    }
}

// ---------------- kernel 6: per-(b,k) gate + projection + LN ----------------
__global__ __launch_bounds__(256) void phrase_kernel(const float* __restrict__ hidden,
                                                     const float* __restrict__ tops,
                                                     const int* __restrict__ topi,
                                                     const float* __restrict__ wg1,
                                                     const float* __restrict__ bg1,
                                                     const float* __restrict__ wg2,
                                                     const float* __restrict__ bg2,
                                                     const float* __restrict__ wp,
                                                     const float* __restrict__ bp,
                                                     const float* __restrict__ gout,
                                                     const float* __restrict__ bout,
                                                     float* __restrict__ gate,
                                                     float* __restrict__ out_embeds) {
    int bk = blockIdx.x;            // 0..255
    int b = bk >> 5;
    int tid = threadIdx.x;
    __shared__ float emb[768];
    __shared__ float red[256];
    __shared__ float bc2[2];

    int idx = topi[bk];
    bool valid = tops[bk] > (NEG_ * 0.5f);
    int tI = idx / 5, tw = idx % 5;
    int jend = min(tI + tw, L_ - 1);
    float inv = 1.0f / (float)(tw + 1);

    for (int c = tid; c < 768; c += 256) {
        float s = 0.f;
        if (valid) {
            for (int l = tI; l <= jend; ++l) s += hidden[(size_t)(b * 512 + l) * 768 + c];
            s *= inv;
        }
        emb[c] = s;
    }
    __syncthreads();

    // gate logits
    float gl_part = 0.f;
    for (int n = tid; n < 384; n += 256) {
        float s = bg1[n];
        for (int c = 0; c < 768; ++c) s += emb[c] * wg1[(size_t)c * 384 + n];
        gl_part += tanhf(s) * wg2[n];
    }
    red[tid] = gl_part;
    __syncthreads();
    for (int s = 128; s > 0; s >>= 1) { if (tid < s) red[tid] += red[tid + s]; __syncthreads(); }
    if (tid == 0) gate[bk] = valid ? (red[0] + bg2[0]) : -1e9f;

    // projection (256 outputs, one per thread)
    float p = bp[tid];
    for (int c = 0; c < 768; ++c) p += emb[c] * wp[(size_t)c * 256 + tid];
    __syncthreads();

    // LN over 256
    red[tid] = p;
    __syncthreads();
    for (int s = 128; s > 0; s >>= 1) { if (tid < s) red[tid] += red[tid + s]; __syncthreads(); }
    if (tid == 0) bc2[0] = red[0] * (1.f / 256.f);
    __syncthreads();
    float m = bc2[0];
    float d = p - m;
    red[tid] = d * d;
    __syncthreads();
    for (int s = 128; s > 0; s >>= 1) { if (tid < s) red[tid] += red[tid + s]; __syncthreads(); }
    if (tid == 0) bc2[1] = red[0] * (1.f / 256.f);
    __syncthreads();
    float rstd = rsqrtf(bc2[1] + EPS_);
    out_embeds[(size_t)bk * 256 + tid] = d * rstd * gout[tid] + bout[tid];
}

// ---------------- kernel 7: softmax over K per b ----------------
__global__ void attn_kernel(const float* __restrict__ gate, float* __restrict__ out_attn) {
    int b = threadIdx.x;
    if (b < 8) {
        float mx = -FLT_MAX;
        for (int k = 0; k < 32; ++k) mx = fmaxf(mx, gate[b * 32 + k]);
        float e[32];
        float s = 0.f;
        for (int k = 0; k < 32; ++k) { e[k] = expf(gate[b * 32 + k] - mx); s += e[k]; }
        float inv = 1.f / s;
        for (int k = 0; k < 32; ++k) out_attn[b * 32 + k] = e[k] * inv;
    }
}

extern "C" void kernel_launch(void* const* d_in, const int* in_sizes, int n_in,
                              void* d_out, int out_size, void* d_ws, size_t ws_size,
                              hipStream_t stream) {
    const float* hidden = (const float*)d_in[0];
    const int*   amask  = (const int*)d_in[1];
    const float* w1     = (const float*)d_in[2];
    const float* b1     = (const float*)d_in[3];
    const float* g1     = (const float*)d_in[4];
    const float* beta1  = (const float*)d_in[5];
    const float* w2     = (const float*)d_in[6];
    const float* b2     = (const float*)d_in[7];
    const float* wp     = (const float*)d_in[8];
    const float* bp     = (const float*)d_in[9];
    const float* wg1    = (const float*)d_in[10];
    const float* bg1    = (const float*)d_in[11];
    const float* wg2    = (const float*)d_in[12];
    const float* bg2    = (const float*)d_in[13];
    const float* gout   = (const float*)d_in[14];
    const float* bout   = (const float*)d_in[15];

    float* ws = (float*)d_ws;
    float*     X  = ws + OFF_X;
    _Float16*  ah = (_Float16*)(ws + OFF_AH);
    _Float16*  al = (_Float16*)(ws + OFF_AL);
    _Float16*  bh = (_Float16*)(ws + OFF_BH);
    _Float16*  bl = (_Float16*)(ws + OFF_BL);
    float* sc = ws + OFF_SC;
    float* ts = ws + OFF_TS;
    int*   ti = (int*)(ws + OFF_TI);
    float* gl = ws + OFF_GL;

    float* out = (float*)d_out;
    float* out_embeds = out;                   // 8*32*256 = 65536
    float* out_masks  = out + 65536;           // 256
    float* out_attn   = out + 65792;           // 256
    float* out_scores = out + 66048;           // 256
    float* out_spans  = out + 66304;           // 512

    split_hidden_kernel<<<3072, 256, 0, stream>>>(hidden, ah, al);
    build_wt_kernel<<<dim3(36, 12), 256, 0, stream>>>(w1, bh, bl);
    mfma_gemm_kernel<<<dim3(32, 18), 256, 0, stream>>>(ah, al, bh, bl, X);
    score_kernel<<<1024, 256, 0, stream>>>(X, amask, b1, g1, beta1, w2, b2, sc);
    topk_kernel<<<8, 256, 0, stream>>>(sc, ts, ti, out_masks, out_scores, out_spans);
    phrase_kernel<<<256, 256, 0, stream>>>(hidden, ts, ti, wg1, bg1, wg2, bg2,
                                           wp, bp, gout, bout, gl, out_embeds);
    attn_kernel<<<1, 64, 0, stream>>>(gl, out_attn);
}

// Round 4
// 286.311 us; speedup vs baseline: 1.7652x; 1.0961x over previous
//
#include <hip/hip_runtime.h>
#include <float.h>
#include <math.h>

#define B_   8
#define L_   512
#define H_   768
#define W_   5
#define K_   32
#define P_   256
#define EPS_ 1e-5f
#define NEG_ -1e30f

typedef _Float16 half8 __attribute__((ext_vector_type(8)));
typedef _Float16 half4v __attribute__((ext_vector_type(4)));
typedef float floatx4 __attribute__((ext_vector_type(4)));

// ---------------- ws layout (float units) ----------------
static const size_t OFF_X   = 0;                   // 4096*2304 f32
static const size_t OFF_AH  = 9437184;             // 4096*768 f16 (hi)
static const size_t OFF_AL  = 11010048;            // 4096*768 f16 (lo)
static const size_t OFF_BH  = 12582912;            // 2304*768 f16 (WtT hi)
static const size_t OFF_BL  = 13467648;            // 2304*768 f16 (WtT lo)
static const size_t OFF_SC  = 14352384;            // 8*2560 scores
static const size_t OFF_TS  = 14372864;            // 256
static const size_t OFF_TI  = 14373120;            // 256 (int)
static const size_t OFF_GL  = 14373376;            // 256
static const size_t OFF_EMB = 14373632;            // 256*768
static const size_t OFF_Y   = 14570240;            // 256*640

#define A_SCALE 8.0f
#define B_SCALE 64.0f
#define INV_SCALE (1.0f / 512.0f)

// ---------------- kernel 1: split hidden -> f16 hi/lo (scaled x8) ----------------
__global__ __launch_bounds__(256) void split_hidden_kernel(const float* __restrict__ hid,
                                                           _Float16* __restrict__ ah,
                                                           _Float16* __restrict__ al) {
    int idx = (blockIdx.x * 256 + threadIdx.x) * 4;   // total 3,145,728 elems -> 3072 blocks
    float4 x = *(const float4*)(hid + idx);
    float xs[4] = {x.x * A_SCALE, x.y * A_SCALE, x.z * A_SCALE, x.w * A_SCALE};
    half4v h, l;
#pragma unroll
    for (int i = 0; i < 4; ++i) {
        _Float16 hi = (_Float16)xs[i];
        h[i] = hi;
        l[i] = (_Float16)(xs[i] - (float)hi);
    }
    *(half4v*)(ah + idx) = h;
    *(half4v*)(al + idx) = l;
}

// ---------------- kernel 2: build transposed combined weight, f16 hi/lo (scaled x64) ----
__global__ __launch_bounds__(256) void build_wt_kernel(const float* __restrict__ w1,
                                                       _Float16* __restrict__ bh,
                                                       _Float16* __restrict__ bl) {
    __shared__ float ld[64][65];
    int n0 = blockIdx.x * 64;    // 36 blocks
    int k0 = blockIdx.y * 64;    // 12 blocks
    int t = threadIdx.x;
    int rsel = n0 / 768;         // block-uniform (768 % 64 == 0)
    int c0 = n0 - rsel * 768;
#pragma unroll 4
    for (int r = 0; r < 16; ++r) {
        int idx = r * 256 + t;
        int kk = idx >> 6, nn = idx & 63;
        int k = k0 + kk, c = c0 + nn;
        float v;
        if (rsel == 0)      v = w1[(size_t)k * 768 + c] - w1[(size_t)(2304 + k) * 768 + c];
        else if (rsel == 1) v = w1[(size_t)(768 + k) * 768 + c] + w1[(size_t)(2304 + k) * 768 + c];
        else                v = w1[(size_t)(1536 + k) * 768 + c];
        ld[kk][nn] = v * B_SCALE;
    }
    __syncthreads();
#pragma unroll 4
    for (int r = 0; r < 16; ++r) {
        int idx = r * 256 + t;
        int nn = idx >> 6, kk = idx & 63;
        float v = ld[kk][nn];
        _Float16 h = (_Float16)v;
        _Float16 lo = (_Float16)(v - (float)h);
        size_t o = (size_t)(n0 + nn) * 768 + k0 + kk;
        bh[o] = h;
        bl[o] = lo;
    }
}

// ---------------- kernel 3: split-f16 MFMA GEMM ----------------
typedef const __attribute__((address_space(1))) void* gas_ptr;
typedef __attribute__((address_space(3))) void* las_ptr;
__device__ __forceinline__ void async_ld16(const _Float16* g, _Float16* l) {
    __builtin_amdgcn_global_load_lds((gas_ptr)g, (las_ptr)l, 16, 0, 0);
}

__global__ __launch_bounds__(256) void mfma_gemm_kernel(const _Float16* __restrict__ Ah,
                                                        const _Float16* __restrict__ Al,
                                                        const _Float16* __restrict__ Bh,
                                                        const _Float16* __restrict__ Bl,
                                                        float* __restrict__ C) {
    __shared__ _Float16 sAh[128 * 32];
    __shared__ _Float16 sAl[128 * 32];
    __shared__ _Float16 sBh[128 * 32];
    __shared__ _Float16 sBl[128 * 32];
    int tid = threadIdx.x;
    int lane = tid & 63;
    int wave = tid >> 6;
    int m0 = blockIdx.x * 128, n0 = blockIdx.y * 128;

    const _Float16* src = (wave == 0) ? Ah : (wave == 1) ? Al : (wave == 2) ? Bh : Bl;
    _Float16* dst = (wave == 0) ? sAh : (wave == 1) ? sAl : (wave == 2) ? sBh : sBl;
    int row0 = (wave < 2) ? m0 : n0;
    int qg = (lane & 3) ^ ((lane >> 3) & 3);            // swizzled source k-group
    const _Float16* gp = src + (size_t)(row0 + (lane >> 2)) * 768 + qg * 8;

    int wr = wave >> 1, wc = wave & 1;
    int off_lane = (lane & 15) * 64 + (((lane >> 4) ^ ((lane >> 1) & 3)) * 16);  // bytes
    const char* pAh = (const char*)sAh + wr * 4096 + off_lane;
    const char* pAl = (const char*)sAl + wr * 4096 + off_lane;
    const char* pBh = (const char*)sBh + wc * 4096 + off_lane;
    const char* pBl = (const char*)sBl + wc * 4096 + off_lane;

    floatx4 acc[4][4];
#pragma unroll
    for (int i = 0; i < 4; ++i)
#pragma unroll
        for (int j = 0; j < 4; ++j)
            acc[i][j] = (floatx4){0.f, 0.f, 0.f, 0.f};

    for (int k0 = 0; k0 < 768; k0 += 32) {
        __syncthreads();
#pragma unroll
        for (int c = 0; c < 8; ++c)
            async_ld16(gp + k0 + (size_t)c * 16 * 768, dst + c * 512);
        __syncthreads();

        half8 a_h[4], a_l[4], b_h[4], b_l[4];
#pragma unroll
        for (int i = 0; i < 4; ++i) {
            a_h[i] = *(const half8*)(pAh + i * 1024);
            a_l[i] = *(const half8*)(pAl + i * 1024);
            b_h[i] = *(const half8*)(pBh + i * 1024);
            b_l[i] = *(const half8*)(pBl + i * 1024);
        }
#pragma unroll
        for (int i = 0; i < 4; ++i)
#pragma unroll
            for (int j = 0; j < 4; ++j) {
                acc[i][j] = __builtin_amdgcn_mfma_f32_16x16x32_f16(a_h[i], b_h[j], acc[i][j], 0, 0, 0);
                acc[i][j] = __builtin_amdgcn_mfma_f32_16x16x32_f16(a_h[i], b_l[j], acc[i][j], 0, 0, 0);
                acc[i][j] = __builtin_amdgcn_mfma_f32_16x16x32_f16(a_l[i], b_h[j], acc[i][j], 0, 0, 0);
            }
    }

    int colc = lane & 15, quad = lane >> 4;
#pragma unroll
    for (int i = 0; i < 4; ++i) {
#pragma unroll
        for (int r = 0; r < 4; ++r) {
            int row = m0 + wr * 64 + i * 16 + quad * 4 + r;
            float* Cp = C + (size_t)row * 2304 + n0 + wc * 64 + colc;
#pragma unroll
            for (int j = 0; j < 4; ++j)
                Cp[j * 16] = acc[i][j][r] * INV_SCALE;
        }
    }
}

// ---------------- kernel 4: per-(b,i) span scores, one wave per (b,i) ----------------
__global__ __launch_bounds__(256) void score_kernel(const float* __restrict__ X,
                                                    const int* __restrict__ mask,
                                                    const float* __restrict__ b1,
                                                    const float* __restrict__ g1,
                                                    const float* __restrict__ beta1,
                                                    const float* __restrict__ w2,
                                                    const float* __restrict__ b2,
                                                    float* __restrict__ scores) {
    int wave = threadIdx.x >> 6;
    int lane = threadIdx.x & 63;
    int bi = blockIdx.x * 4 + wave;    // 0..4095
    int b = bi >> 9, i = bi & 511;

    float a[12], b1c[12], g1c[12], btc[12], w2c[12], ss[12], e[12];
    const float* Xrow = X + (size_t)bi * 2304;
#pragma unroll
    for (int q = 0; q < 12; ++q) {
        int c = lane + q * 64;
        a[q]   = Xrow[c];
        b1c[q] = b1[c];
        g1c[q] = g1[c];
        btc[q] = beta1[c];
        w2c[q] = w2[c];
        ss[q]  = 0.f;
    }
    float bias2 = b2[0];
    int jcur = i - 1;
    float sc_loc[W_];

    for (int w = 0; w < W_; ++w) {
        int j = min(i + w, 511);
        const float* Xj = X + (size_t)(b * 512 + j) * 2304;
        if (j > jcur) {
#pragma unroll
            for (int q = 0; q < 12; ++q) {
                int c = lane + q * 64;
                ss[q] += Xj[1536 + c];
                e[q]   = Xj[768 + c];
            }
            jcur = j;
        }
        float invw = 1.0f / (float)(w + 1);
        float h[12];
        float psum = 0.f;
#pragma unroll
        for (int q = 0; q < 12; ++q) {
            h[q] = a[q] + e[q] + ss[q] * invw + b1c[q];
            psum += h[q];
        }
#pragma unroll
        for (int m = 1; m < 64; m <<= 1) psum += __shfl_xor(psum, m, 64);
        float mean = psum * (1.f / 768.f);

        float pv = 0.f;
#pragma unroll
        for (int q = 0; q < 12; ++q) {
            float d = h[q] - mean;
            pv += d * d;
        }
#pragma unroll
        for (int m = 1; m < 64; m <<= 1) pv += __shfl_xor(pv, m, 64);
        float rstd = rsqrtf(pv * (1.f / 768.f) + EPS_);

        float pd = 0.f;
#pragma unroll
        for (int q = 0; q < 12; ++q) {
            float d = h[q] - mean;
            float y = fmaxf(d * rstd * g1c[q] + btc[q], 0.f);
            pd += y * w2c[q];
        }
#pragma unroll
        for (int m = 1; m < 64; m <<= 1) pd += __shfl_xor(pd, m, 64);
        sc_loc[w] = pd + bias2;
    }

    if (lane < W_) {
        int w = lane;
        bool ok = (i + w) < 512;
        if (ok) {
            for (int t = 0; t <= w; ++t) ok = ok && (mask[b * 512 + i + t] != 0);
        }
        scores[b * 2560 + i * 5 + w] = ok ? sc_loc[w] : NEG_;
    }
}

// ---------------- kernel 5: per-b top-32 (stable, lowest-index ties) ----------------
__global__ __launch_bounds__(256) void topk_kernel(const float* __restrict__ scores,
                                                   float* __restrict__ tops,
                                                   int* __restrict__ topi,
                                                   float* __restrict__ out_masks,
                                                   float* __restrict__ out_scores,
                                                   float* __restrict__ out_spans) {
    int b = blockIdx.x;
    int tid = threadIdx.x;
    int lane = tid & 63;
    int wv = tid >> 6;
    __shared__ float sc[2560];
    __shared__ float wv_v[4];
    __shared__ int   wv_i[4];
    for (int t = tid; t < 2560; t += 256) sc[t] = scores[b * 2560 + t];
    __syncthreads();

    for (int k = 0; k < K_; ++k) {
        float bv = -FLT_MAX; int bix = 1 << 30;
        for (int t = tid; t < 2560; t += 256) {
            float v = sc[t];
            if (v > bv || (v == bv && t < bix)) { bv = v; bix = t; }
        }
#pragma unroll
        for (int m = 1; m < 64; m <<= 1) {
            float v2 = __shfl_xor(bv, m, 64);
            int   i2 = __shfl_xor(bix, m, 64);
            if (v2 > bv || (v2 == bv && i2 < bix)) { bv = v2; bix = i2; }
        }
        if (lane == 0) { wv_v[wv] = bv; wv_i[wv] = bix; }
        __syncthreads();
        if (tid == 0) {
            float tv = wv_v[0]; int tix = wv_i[0];
            for (int q = 1; q < 4; ++q) {
                if (wv_v[q] > tv || (wv_v[q] == tv && wv_i[q] < tix)) { tv = wv_v[q]; tix = wv_i[q]; }
            }
            tops[b * 32 + k] = tv;
            topi[b * 32 + k] = tix;
            bool m = tv > (NEG_ * 0.5f);
            out_masks[b * 32 + k] = m ? 1.0f : 0.0f;
            out_scores[b * 32 + k] = m ? tv : -10.0f;
            int tI = tix / 5, tw = tix % 5;
            out_spans[(b * 32 + k) * 2 + 0] = m ? (float)tI : 0.0f;
            out_spans[(b * 32 + k) * 2 + 1] = m ? (float)(tI + tw) : 0.0f;
            sc[tix] = -FLT_MAX;
        }
        __syncthreads();
    }
}

// ---------------- kernel 6: gather phrase mean-embeddings into Embs[256][768] ----------
__global__ __launch_bounds__(256) void gather_emb_kernel(const float* __restrict__ hidden,
                                                         const float* __restrict__ tops,
                                                         const int* __restrict__ topi,
                                                         float* __restrict__ Embs) {
    int bk = blockIdx.x;            // 0..255
    int b = bk >> 5;
    int tid = threadIdx.x;
    int idx = topi[bk];
    bool valid = tops[bk] > (NEG_ * 0.5f);
    int tI = idx / 5, tw = idx % 5;
    int jend = min(tI + tw, L_ - 1);
    float inv = 1.0f / (float)(tw + 1);
#pragma unroll
    for (int q = 0; q < 3; ++q) {
        int c = tid + q * 256;
        float s = 0.f;
        if (valid) {
            for (int l = tI; l <= jend; ++l) s += hidden[(size_t)(b * 512 + l) * 768 + c];
            s *= inv;
        }
        Embs[(size_t)bk * 768 + c] = s;
    }
}

// ---------------- kernel 7: Y[256][640] = Embs @ [wg1|wp] + [bg1|bp] ----------------
// 32x64 tiles, grid (8,10), 256 threads; thread = 2 rows x 4 cols.
__global__ __launch_bounds__(256) void phrase_gemm_kernel(const float* __restrict__ Embs,
                                                          const float* __restrict__ wg1,
                                                          const float* __restrict__ bg1,
                                                          const float* __restrict__ wp,
                                                          const float* __restrict__ bp,
                                                          float* __restrict__ Y) {
    __shared__ float As[32][34];   // [k][r]
    __shared__ float Bs[32][64];   // [k][c]
    int tid = threadIdx.x;
    int m0 = blockIdx.x * 32;
    int cn0 = blockIdx.y * 64;
    const float* Wp; const float* biasp; int ldw;
    if (cn0 < 384) { Wp = wg1 + cn0;        biasp = bg1 + cn0;        ldw = 384; }
    else           { Wp = wp + (cn0 - 384); biasp = bp + (cn0 - 384); ldw = 256; }

    int tx = tid & 15;       // cols tx*4
    int ty = tid >> 4;       // rows ty*2
    int ar = tid >> 3, akq = (tid & 7) * 4;
    int bk = tid >> 3, bcq = (tid & 7) * 8;
    float acc[2][4] = {};

    for (int k0 = 0; k0 < 768; k0 += 32) {
        float4 av  = *(const float4*)(Embs + (size_t)(m0 + ar) * 768 + k0 + akq);
        float4 bv0 = *(const float4*)(Wp + (size_t)(k0 + bk) * ldw + bcq);
        float4 bv1 = *(const float4*)(Wp + (size_t)(k0 + bk) * ldw + bcq + 4);
        __syncthreads();
        As[akq + 0][ar] = av.x;
        As[akq + 1][ar] = av.y;
        As[akq + 2][ar] = av.z;
        As[akq + 3][ar] = av.w;
        *(float4*)&Bs[bk][bcq]     = bv0;
        *(float4*)&Bs[bk][bcq + 4] = bv1;
        __syncthreads();
#pragma unroll
        for (int kk = 0; kk < 32; ++kk) {
            float2 a = *(const float2*)&As[kk][ty * 2];
            float4 b = *(const float4*)&Bs[kk][tx * 4];
            acc[0][0] += a.x * b.x; acc[0][1] += a.x * b.y; acc[0][2] += a.x * b.z; acc[0][3] += a.x * b.w;
            acc[1][0] += a.y * b.x; acc[1][1] += a.y * b.y; acc[1][2] += a.y * b.z; acc[1][3] += a.y * b.w;
        }
    }
#pragma unroll
    for (int i = 0; i < 2; ++i) {
        float* Yp = Y + (size_t)(m0 + ty * 2 + i) * 640 + cn0 + tx * 4;
        float4 o = make_float4(acc[i][0] + biasp[tx * 4 + 0], acc[i][1] + biasp[tx * 4 + 1],
                               acc[i][2] + biasp[tx * 4 + 2], acc[i][3] + biasp[tx * 4 + 3]);
        *(float4*)Yp = o;
    }
}

// ---------------- kernel 8: per-row gate (tanh . wg2) + LN of projection ----------------
__global__ __launch_bounds__(256) void phrase_post_kernel(const float* __restrict__ Y,
                                                          const float* __restrict__ wg2,
                                                          const float* __restrict__ bg2,
                                                          const float* __restrict__ tops,
                                                          const float* __restrict__ gout,
                                                          const float* __restrict__ bout,
                                                          float* __restrict__ gate,
                                                          float* __restrict__ out_embeds) {
    int wv = threadIdx.x >> 6, lane = threadIdx.x & 63;
    int row = blockIdx.x * 4 + wv;   // 64 blocks -> 256 rows
    const float* Yrow = Y + (size_t)row * 640;

    // gate logit: sum tanh(Y[0..384)) * wg2
    float s = 0.f;
#pragma unroll
    for (int q = 0; q < 6; ++q) {
        int c = lane + q * 64;
        s += tanhf(Yrow[c]) * wg2[c];
    }
#pragma unroll
    for (int m = 1; m < 64; m <<= 1) s += __shfl_xor(s, m, 64);
    if (lane == 0) {
        bool valid = tops[row] > (NEG_ * 0.5f);
        gate[row] = valid ? (s + bg2[0]) : -1e9f;
    }

    // LN over cols 384..639
    float4 p = *(const float4*)(Yrow + 384 + lane * 4);
    float sm = p.x + p.y + p.z + p.w;
#pragma unroll
    for (int m = 1; m < 64; m <<= 1) sm += __shfl_xor(sm, m, 64);
    float mean = sm * (1.f / 256.f);
    float dx = p.x - mean, dy = p.y - mean, dz = p.z - mean, dw = p.w - mean;
    float v = dx * dx + dy * dy + dz * dz + dw * dw;
#pragma unroll
    for (int m = 1; m < 64; m <<= 1) v += __shfl_xor(v, m, 64);
    float rstd = rsqrtf(v * (1.f / 256.f) + EPS_);
    int c = lane * 4;
    float4 o;
    o.x = dx * rstd * gout[c]     + bout[c];
    o.y = dy * rstd * gout[c + 1] + bout[c + 1];
    o.z = dz * rstd * gout[c + 2] + bout[c + 2];
    o.w = dw * rstd * gout[c + 3] + bout[c + 3];
    *(float4*)(out_embeds + (size_t)row * 256 + c) = o;
}

// ---------------- kernel 9: softmax over K per b ----------------
__global__ void attn_kernel(const float* __restrict__ gate, float* __restrict__ out_attn) {
    int b = threadIdx.x;
    if (b < 8) {
        float mx = -FLT_MAX;
        for (int k = 0; k < 32; ++k) mx = fmaxf(mx, gate[b * 32 + k]);
        float e[32];
        float s = 0.f;
        for (int k = 0; k < 32; ++k) { e[k] = expf(gate[b * 32 + k] - mx); s += e[k]; }
        float inv = 1.f / s;
        for (int k = 0; k < 32; ++k) out_attn[b * 32 + k] = e[k] * inv;
    }
}

extern "C" void kernel_launch(void* const* d_in, const int* in_sizes, int n_in,
                              void* d_out, int out_size, void* d_ws, size_t ws_size,
                              hipStream_t stream) {
    const float* hidden = (const float*)d_in[0];
    const int*   amask  = (const int*)d_in[1];
    const float* w1     = (const float*)d_in[2];
    const float* b1     = (const float*)d_in[3];
    const float* g1     = (const float*)d_in[4];
    const float* beta1  = (const float*)d_in[5];
    const float* w2     = (const float*)d_in[6];
    const float* b2     = (const float*)d_in[7];
    const float* wp     = (const float*)d_in[8];
    const float* bp     = (const float*)d_in[9];
    const float* wg1    = (const float*)d_in[10];
    const float* bg1    = (const float*)d_in[11];
    const float* wg2    = (const float*)d_in[12];
    const float* bg2    = (const float*)d_in[13];
    const float* gout   = (const float*)d_in[14];
    const float* bout   = (const float*)d_in[15];

    float* ws = (float*)d_ws;
    float*     X    = ws + OFF_X;
    _Float16*  ah   = (_Float16*)(ws + OFF_AH);
    _Float16*  al   = (_Float16*)(ws + OFF_AL);
    _Float16*  bh   = (_Float16*)(ws + OFF_BH);
    _Float16*  bl   = (_Float16*)(ws + OFF_BL);
    float*     sc   = ws + OFF_SC;
    float*     ts   = ws + OFF_TS;
    int*       ti   = (int*)(ws + OFF_TI);
    float*     gl   = ws + OFF_GL;
    float*     Embs = ws + OFF_EMB;
    float*     Y    = ws + OFF_Y;

    float* out = (float*)d_out;
    float* out_embeds = out;                   // 8*32*256 = 65536
    float* out_masks  = out + 65536;           // 256
    float* out_attn   = out + 65792;           // 256
    float* out_scores = out + 66048;           // 256
    float* out_spans  = out + 66304;           // 512

    split_hidden_kernel<<<3072, 256, 0, stream>>>(hidden, ah, al);
    build_wt_kernel<<<dim3(36, 12), 256, 0, stream>>>(w1, bh, bl);
    mfma_gemm_kernel<<<dim3(32, 18), 256, 0, stream>>>(ah, al, bh, bl, X);
    score_kernel<<<1024, 256, 0, stream>>>(X, amask, b1, g1, beta1, w2, b2, sc);
    topk_kernel<<<8, 256, 0, stream>>>(sc, ts, ti, out_masks, out_scores, out_spans);
    gather_emb_kernel<<<256, 256, 0, stream>>>(hidden, ts, ti, Embs);
    phrase_gemm_kernel<<<dim3(8, 10), 256, 0, stream>>>(Embs, wg1, bg1, wp, bp, Y);
    phrase_post_kernel<<<64, 256, 0, stream>>>(Y, wg2, bg2, ts, gout, bout, gl, out_embeds);
    attn_kernel<<<1, 64, 0, stream>>>(gl, out_attn);
}

// Round 5
// 276.350 us; speedup vs baseline: 1.8288x; 1.0360x over previous
//
#include <hip/hip_runtime.h>
#include <float.h>
#include <math.h>

#define B_   8
#define L_   512
#define H_   768
#define W_   5
#define K_   32
#define P_   256
#define EPS_ 1e-5f
#define NEG_ -1e30f

typedef _Float16 half8 __attribute__((ext_vector_type(8)));
typedef _Float16 half4v __attribute__((ext_vector_type(4)));
typedef float floatx4 __attribute__((ext_vector_type(4)));

// ---------------- ws layout (float units) ----------------
static const size_t OFF_X   = 0;                   // 4096*2304 f32
static const size_t OFF_AH  = 9437184;             // 4096*768 f16 (hi)
static const size_t OFF_AL  = 11010048;            // 4096*768 f16 (lo)
static const size_t OFF_BH  = 12582912;            // 2304*768 f16 (WtT hi)
static const size_t OFF_BL  = 13467648;            // 2304*768 f16 (WtT lo)
static const size_t OFF_SC  = 14352384;            // 8*2560 scores
static const size_t OFF_TS  = 14372864;            // 256
static const size_t OFF_TI  = 14373120;            // 256 (int)
static const size_t OFF_GL  = 14373376;            // 256
static const size_t OFF_EMB = 14373632;            // 256*768
static const size_t OFF_Y   = 14570240;            // 256*640

#define A_SCALE 8.0f
#define B_SCALE 64.0f
#define INV_SCALE (1.0f / 512.0f)

// ---------------- kernel 1: fused prep: split hidden + build WtT hi/lo ----------------
__global__ __launch_bounds__(256) void prep_kernel(const float* __restrict__ hid,
                                                   const float* __restrict__ w1,
                                                   _Float16* __restrict__ ah,
                                                   _Float16* __restrict__ al,
                                                   _Float16* __restrict__ bh,
                                                   _Float16* __restrict__ bl) {
    __shared__ float ld[64][65];
    if (blockIdx.x < 3072) {
        // split hidden -> f16 hi/lo (scaled x8)
        int idx = (blockIdx.x * 256 + threadIdx.x) * 4;
        float4 x = *(const float4*)(hid + idx);
        float xs[4] = {x.x * A_SCALE, x.y * A_SCALE, x.z * A_SCALE, x.w * A_SCALE};
        half4v h, l;
#pragma unroll
        for (int i = 0; i < 4; ++i) {
            _Float16 hi = (_Float16)xs[i];
            h[i] = hi;
            l[i] = (_Float16)(xs[i] - (float)hi);
        }
        *(half4v*)(ah + idx) = h;
        *(half4v*)(al + idx) = l;
    } else {
        // build transposed combined weight (scaled x64)
        int bid = blockIdx.x - 3072;          // 0..431
        int n0 = (bid / 12) * 64;
        int k0 = (bid % 12) * 64;
        int t = threadIdx.x;
        int rsel = n0 / 768;
        int c0 = n0 - rsel * 768;
#pragma unroll 4
        for (int r = 0; r < 16; ++r) {
            int idx = r * 256 + t;
            int kk = idx >> 6, nn = idx & 63;
            int k = k0 + kk, c = c0 + nn;
            float v;
            if (rsel == 0)      v = w1[(size_t)k * 768 + c] - w1[(size_t)(2304 + k) * 768 + c];
            else if (rsel == 1) v = w1[(size_t)(768 + k) * 768 + c] + w1[(size_t)(2304 + k) * 768 + c];
            else                v = w1[(size_t)(1536 + k) * 768 + c];
            ld[kk][nn] = v * B_SCALE;
        }
        __syncthreads();
#pragma unroll 4
        for (int r = 0; r < 16; ++r) {
            int idx = r * 256 + t;
            int nn = idx >> 6, kk = idx & 63;
            float v = ld[kk][nn];
            _Float16 h = (_Float16)v;
            _Float16 lo = (_Float16)(v - (float)h);
            size_t o = (size_t)(n0 + nn) * 768 + k0 + kk;
            bh[o] = h;
            bl[o] = lo;
        }
    }
}

// ---------------- kernel 2: split-f16 MFMA GEMM, 128x64 tile, LDS double-buffer ------
typedef const __attribute__((address_space(1))) void* gas_ptr;
typedef __attribute__((address_space(3))) void* las_ptr;
__device__ __forceinline__ void async_ld16(const _Float16* g, _Float16* l) {
    __builtin_amdgcn_global_load_lds((gas_ptr)g, (las_ptr)l, 16, 0, 0);
}

__global__ __launch_bounds__(256) void mfma_gemm_kernel(const _Float16* __restrict__ Ah,
                                                        const _Float16* __restrict__ Al,
                                                        const _Float16* __restrict__ Bh,
                                                        const _Float16* __restrict__ Bl,
                                                        float* __restrict__ C) {
    __shared__ _Float16 sAh[2 * 4096];   // [parity][128 rows x 32 k]
    __shared__ _Float16 sAl[2 * 4096];
    __shared__ _Float16 sBh[2 * 2048];   // [parity][64 rows x 32 k]
    __shared__ _Float16 sBl[2 * 2048];
    int tid = threadIdx.x;
    int lane = tid & 63;
    int wave = tid >> 6;
    int m0 = blockIdx.x * 128, n0 = blockIdx.y * 64;

    // staging role: w0->Ah(8 chunks), w1->Al(8), w2->Bh(4), w3->Bl(4)
    const _Float16* src = (wave == 0) ? Ah : (wave == 1) ? Al : (wave == 2) ? Bh : Bl;
    _Float16* dstb = (wave == 0) ? sAh : (wave == 1) ? sAl : (wave == 2) ? sBh : sBl;
    int psz  = (wave < 2) ? 4096 : 2048;
    int nch  = (wave < 2) ? 8 : 4;
    int row0 = (wave < 2) ? m0 : n0;
    int qg = (lane & 3) ^ ((lane >> 3) & 3);            // swizzled source k-group
    const _Float16* gp = src + (size_t)(row0 + (lane >> 2)) * 768 + qg * 8;

    // compute role: wave -> 64x32 quadrant
    int wr = wave >> 1, wc = wave & 1;
    int off_lane = (lane & 15) * 64 + (((lane >> 4) ^ ((lane >> 1) & 3)) * 16);  // bytes
    floatx4 acc[4][2];
#pragma unroll
    for (int i = 0; i < 4; ++i)
#pragma unroll
        for (int j = 0; j < 2; ++j)
            acc[i][j] = (floatx4){0.f, 0.f, 0.f, 0.f};

    // prologue: stage k0=0 into parity 0
#pragma unroll
    for (int c = 0; c < 8; ++c) {
        if (c < nch) async_ld16(gp + (size_t)c * 16 * 768, dstb + c * 512);
    }

    int parity = 0;
    for (int k0 = 0; k0 < 768; k0 += 32) {
        __syncthreads();   // drains vmcnt -> staged tile ready; prev compute done
        if (k0 + 32 < 768) {
            _Float16* dst = dstb + (parity ^ 1) * psz;
            const _Float16* g = gp + k0 + 32;
#pragma unroll
            for (int c = 0; c < 8; ++c) {
                if (c < nch) async_ld16(g + (size_t)c * 16 * 768, dst + c * 512);
            }
        }

        const char* bAh = (const char*)sAh + parity * 8192 + wr * 4096 + off_lane;
        const char* bAl = (const char*)sAl + parity * 8192 + wr * 4096 + off_lane;
        const char* bBh = (const char*)sBh + parity * 4096 + wc * 2048 + off_lane;
        const char* bBl = (const char*)sBl + parity * 4096 + wc * 2048 + off_lane;
        half8 a_h[4], a_l[4], b_h[2], b_l[2];
#pragma unroll
        for (int i = 0; i < 4; ++i) {
            a_h[i] = *(const half8*)(bAh + i * 1024);
            a_l[i] = *(const half8*)(bAl + i * 1024);
        }
#pragma unroll
        for (int j = 0; j < 2; ++j) {
            b_h[j] = *(const half8*)(bBh + j * 1024);
            b_l[j] = *(const half8*)(bBl + j * 1024);
        }
#pragma unroll
        for (int i = 0; i < 4; ++i)
#pragma unroll
            for (int j = 0; j < 2; ++j) {
                acc[i][j] = __builtin_amdgcn_mfma_f32_16x16x32_f16(a_h[i], b_h[j], acc[i][j], 0, 0, 0);
                acc[i][j] = __builtin_amdgcn_mfma_f32_16x16x32_f16(a_h[i], b_l[j], acc[i][j], 0, 0, 0);
                acc[i][j] = __builtin_amdgcn_mfma_f32_16x16x32_f16(a_l[i], b_h[j], acc[i][j], 0, 0, 0);
            }
        parity ^= 1;
    }

    int colc = lane & 15, quad = lane >> 4;
#pragma unroll
    for (int i = 0; i < 4; ++i) {
#pragma unroll
        for (int r = 0; r < 4; ++r) {
            int row = m0 + wr * 64 + i * 16 + quad * 4 + r;
            float* Cp = C + (size_t)row * 2304 + n0 + wc * 32 + colc;
#pragma unroll
            for (int j = 0; j < 2; ++j)
                Cp[j * 16] = acc[i][j][r] * INV_SCALE;
        }
    }
}

// ---------------- kernel 3: per-(b,i) span scores, one wave per (b,i), float4 ---------
__global__ __launch_bounds__(256) void score_kernel(const float* __restrict__ X,
                                                    const int* __restrict__ mask,
                                                    const float* __restrict__ b1,
                                                    const float* __restrict__ g1,
                                                    const float* __restrict__ beta1,
                                                    const float* __restrict__ w2,
                                                    const float* __restrict__ b2,
                                                    float* __restrict__ scores) {
    int wave = threadIdx.x >> 6;
    int lane = threadIdx.x & 63;
    int bi = blockIdx.x * 4 + wave;    // 0..4095
    int b = bi >> 9, i = bi & 511;

    float4 a[3], b1c[3], g1c[3], btc[3], w2c[3], ss[3], e[3];
    const float4* Xrow = (const float4*)(X + (size_t)bi * 2304);
#pragma unroll
    for (int q = 0; q < 3; ++q) {
        int f = lane + q * 64;
        a[q]   = Xrow[f];
        b1c[q] = ((const float4*)b1)[f];
        g1c[q] = ((const float4*)g1)[f];
        btc[q] = ((const float4*)beta1)[f];
        w2c[q] = ((const float4*)w2)[f];
        ss[q]  = make_float4(0.f, 0.f, 0.f, 0.f);
    }
    float bias2 = b2[0];
    int jcur = i - 1;
    float sc_loc[W_];

    for (int w = 0; w < W_; ++w) {
        int j = min(i + w, 511);
        const float4* Xj = (const float4*)(X + (size_t)(b * 512 + j) * 2304);
        if (j > jcur) {
#pragma unroll
            for (int q = 0; q < 3; ++q) {
                int f = lane + q * 64;
                float4 cc = Xj[384 + f];
                ss[q].x += cc.x; ss[q].y += cc.y; ss[q].z += cc.z; ss[q].w += cc.w;
                e[q] = Xj[192 + f];
            }
            jcur = j;
        }
        float invw = 1.0f / (float)(w + 1);
        float4 h[3];
        float psum = 0.f;
#pragma unroll
        for (int q = 0; q < 3; ++q) {
            h[q].x = a[q].x + e[q].x + ss[q].x * invw + b1c[q].x;
            h[q].y = a[q].y + e[q].y + ss[q].y * invw + b1c[q].y;
            h[q].z = a[q].z + e[q].z + ss[q].z * invw + b1c[q].z;
            h[q].w = a[q].w + e[q].w + ss[q].w * invw + b1c[q].w;
            psum += h[q].x + h[q].y + h[q].z + h[q].w;
        }
#pragma unroll
        for (int m = 1; m < 64; m <<= 1) psum += __shfl_xor(psum, m, 64);
        float mean = psum * (1.f / 768.f);

        float pv = 0.f;
#pragma unroll
        for (int q = 0; q < 3; ++q) {
            float dx = h[q].x - mean, dy = h[q].y - mean, dz = h[q].z - mean, dw = h[q].w - mean;
            pv += dx * dx + dy * dy + dz * dz + dw * dw;
        }
#pragma unroll
        for (int m = 1; m < 64; m <<= 1) pv += __shfl_xor(pv, m, 64);
        float rstd = rsqrtf(pv * (1.f / 768.f) + EPS_);

        float pd = 0.f;
#pragma unroll
        for (int q = 0; q < 3; ++q) {
            float yx = fmaxf((h[q].x - mean) * rstd * g1c[q].x + btc[q].x, 0.f);
            float yy = fmaxf((h[q].y - mean) * rstd * g1c[q].y + btc[q].y, 0.f);
            float yz = fmaxf((h[q].z - mean) * rstd * g1c[q].z + btc[q].z, 0.f);
            float yw = fmaxf((h[q].w - mean) * rstd * g1c[q].w + btc[q].w, 0.f);
            pd += yx * w2c[q].x + yy * w2c[q].y + yz * w2c[q].z + yw * w2c[q].w;
        }
#pragma unroll
        for (int m = 1; m < 64; m <<= 1) pd += __shfl_xor(pd, m, 64);
        sc_loc[w] = pd + bias2;
    }

    if (lane < W_) {
        int w = lane;
        bool ok = (i + w) < 512;
        if (ok) {
            for (int t = 0; t <= w; ++t) ok = ok && (mask[b * 512 + i + t] != 0);
        }
        scores[b * 2560 + i * 5 + w] = ok ? sc_loc[w] : NEG_;
    }
}

// ---------------- kernel 4: per-b top-32 (stable, lowest-index ties) ----------------
__global__ __launch_bounds__(256) void topk_kernel(const float* __restrict__ scores,
                                                   float* __restrict__ tops,
                                                   int* __restrict__ topi,
                                                   float* __restrict__ out_masks,
                                                   float* __restrict__ out_scores,
                                                   float* __restrict__ out_spans) {
    int b = blockIdx.x;
    int tid = threadIdx.x;
    int lane = tid & 63;
    int wv = tid >> 6;
    __shared__ float sc[2560];
    __shared__ float wv_v[4];
    __shared__ int   wv_i[4];
    for (int t = tid; t < 2560; t += 256) sc[t] = scores[b * 2560 + t];
    __syncthreads();

    for (int k = 0; k < K_; ++k) {
        float bv = -FLT_MAX; int bix = 1 << 30;
        for (int t = tid; t < 2560; t += 256) {
            float v = sc[t];
            if (v > bv || (v == bv && t < bix)) { bv = v; bix = t; }
        }
#pragma unroll
        for (int m = 1; m < 64; m <<= 1) {
            float v2 = __shfl_xor(bv, m, 64);
            int   i2 = __shfl_xor(bix, m, 64);
            if (v2 > bv || (v2 == bv && i2 < bix)) { bv = v2; bix = i2; }
        }
        if (lane == 0) { wv_v[wv] = bv; wv_i[wv] = bix; }
        __syncthreads();
        if (tid == 0) {
            float tv = wv_v[0]; int tix = wv_i[0];
            for (int q = 1; q < 4; ++q) {
                if (wv_v[q] > tv || (wv_v[q] == tv && wv_i[q] < tix)) { tv = wv_v[q]; tix = wv_i[q]; }
            }
            tops[b * 32 + k] = tv;
            topi[b * 32 + k] = tix;
            bool m = tv > (NEG_ * 0.5f);
            out_masks[b * 32 + k] = m ? 1.0f : 0.0f;
            out_scores[b * 32 + k] = m ? tv : -10.0f;
            int tI = tix / 5, tw = tix % 5;
            out_spans[(b * 32 + k) * 2 + 0] = m ? (float)tI : 0.0f;
            out_spans[(b * 32 + k) * 2 + 1] = m ? (float)(tI + tw) : 0.0f;
            sc[tix] = -FLT_MAX;
        }
        __syncthreads();
    }
}

// ---------------- kernel 5: gather phrase mean-embeddings into Embs[256][768] ---------
__global__ __launch_bounds__(256) void gather_emb_kernel(const float* __restrict__ hidden,
                                                         const float* __restrict__ tops,
                                                         const int* __restrict__ topi,
                                                         float* __restrict__ Embs) {
    int bk = blockIdx.x;            // 0..255
    int b = bk >> 5;
    int tid = threadIdx.x;
    int idx = topi[bk];
    bool valid = tops[bk] > (NEG_ * 0.5f);
    int tI = idx / 5, tw = idx % 5;
    int jend = min(tI + tw, L_ - 1);
    float inv = 1.0f / (float)(tw + 1);
#pragma unroll
    for (int q = 0; q < 3; ++q) {
        int c = tid + q * 256;
        float s = 0.f;
        if (valid) {
            for (int l = tI; l <= jend; ++l) s += hidden[(size_t)(b * 512 + l) * 768 + c];
            s *= inv;
        }
        Embs[(size_t)bk * 768 + c] = s;
    }
}

// ---------------- kernel 6: Y[256][640] = Embs @ [wg1|wp] + [bg1|bp] ----------------
__global__ __launch_bounds__(256) void phrase_gemm_kernel(const float* __restrict__ Embs,
                                                          const float* __restrict__ wg1,
                                                          const float* __restrict__ bg1,
                                                          const float* __restrict__ wp,
                                                          const float* __restrict__ bp,
                                                          float* __restrict__ Y) {
    __shared__ float As[32][34];   // [k][r]
    __shared__ float Bs[32][64];   // [k][c]
    int tid = threadIdx.x;
    int m0 = blockIdx.x * 32;
    int cn0 = blockIdx.y * 64;
    const float* Wp; const float* biasp; int ldw;
    if (cn0 < 384) { Wp = wg1 + cn0;        biasp = bg1 + cn0;        ldw = 384; }
    else           { Wp = wp + (cn0 - 384); biasp = bp + (cn0 - 384); ldw = 256; }

    int tx = tid & 15;       // cols tx*4
    int ty = tid >> 4;       // rows ty*2
    int ar = tid >> 3, akq = (tid & 7) * 4;
    int bk = tid >> 3, bcq = (tid & 7) * 8;
    float acc[2][4] = {};

    for (int k0 = 0; k0 < 768; k0 += 32) {
        float4 av  = *(const float4*)(Embs + (size_t)(m0 + ar) * 768 + k0 + akq);
        float4 bv0 = *(const float4*)(Wp + (size_t)(k0 + bk) * ldw + bcq);
        float4 bv1 = *(const float4*)(Wp + (size_t)(k0 + bk) * ldw + bcq + 4);
        __syncthreads();
        As[akq + 0][ar] = av.x;
        As[akq + 1][ar] = av.y;
        As[akq + 2][ar] = av.z;
        As[akq + 3][ar] = av.w;
        *(float4*)&Bs[bk][bcq]     = bv0;
        *(float4*)&Bs[bk][bcq + 4] = bv1;
        __syncthreads();
#pragma unroll
        for (int kk = 0; kk < 32; ++kk) {
            float2 a = *(const float2*)&As[kk][ty * 2];
            float4 b = *(const float4*)&Bs[kk][tx * 4];
            acc[0][0] += a.x * b.x; acc[0][1] += a.x * b.y; acc[0][2] += a.x * b.z; acc[0][3] += a.x * b.w;
            acc[1][0] += a.y * b.x; acc[1][1] += a.y * b.y; acc[1][2] += a.y * b.z; acc[1][3] += a.y * b.w;
        }
    }
#pragma unroll
    for (int i = 0; i < 2; ++i) {
        float* Yp = Y + (size_t)(m0 + ty * 2 + i) * 640 + cn0 + tx * 4;
        float4 o = make_float4(acc[i][0] + biasp[tx * 4 + 0], acc[i][1] + biasp[tx * 4 + 1],
                               acc[i][2] + biasp[tx * 4 + 2], acc[i][3] + biasp[tx * 4 + 3]);
        *(float4*)Yp = o;
    }
}

// ---------------- kernel 7: per-row gate (tanh . wg2) + LN of projection --------------
__global__ __launch_bounds__(256) void phrase_post_kernel(const float* __restrict__ Y,
                                                          const float* __restrict__ wg2,
                                                          const float* __restrict__ bg2,
                                                          const float* __restrict__ tops,
                                                          const float* __restrict__ gout,
                                                          const float* __restrict__ bout,
                                                          float* __restrict__ gate,
                                                          float* __restrict__ out_embeds) {
    int wv = threadIdx.x >> 6, lane = threadIdx.x & 63;
    int row = blockIdx.x * 4 + wv;   // 64 blocks -> 256 rows
    const float* Yrow = Y + (size_t)row * 640;

    float s = 0.f;
#pragma unroll
    for (int q = 0; q < 6; ++q) {
        int c = lane + q * 64;
        s += tanhf(Yrow[c]) * wg2[c];
    }
#pragma unroll
    for (int m = 1; m < 64; m <<= 1) s += __shfl_xor(s, m, 64);
    if (lane == 0) {
        bool valid = tops[row] > (NEG_ * 0.5f);
        gate[row] = valid ? (s + bg2[0]) : -1e9f;
    }

    float4 p = *(const float4*)(Yrow + 384 + lane * 4);
    float sm = p.x + p.y + p.z + p.w;
#pragma unroll
    for (int m = 1; m < 64; m <<= 1) sm += __shfl_xor(sm, m, 64);
    float mean = sm * (1.f / 256.f);
    float dx = p.x - mean, dy = p.y - mean, dz = p.z - mean, dw = p.w - mean;
    float v = dx * dx + dy * dy + dz * dz + dw * dw;
#pragma unroll
    for (int m = 1; m < 64; m <<= 1) v += __shfl_xor(v, m, 64);
    float rstd = rsqrtf(v * (1.f / 256.f) + EPS_);
    int c = lane * 4;
    float4 o;
    o.x = dx * rstd * gout[c]     + bout[c];
    o.y = dy * rstd * gout[c + 1] + bout[c + 1];
    o.z = dz * rstd * gout[c + 2] + bout[c + 2];
    o.w = dw * rstd * gout[c + 3] + bout[c + 3];
    *(float4*)(out_embeds + (size_t)row * 256 + c) = o;
}

// ---------------- kernel 8: softmax over K per b ----------------
__global__ void attn_kernel(const float* __restrict__ gate, float* __restrict__ out_attn) {
    int b = threadIdx.x;
    if (b < 8) {
        float mx = -FLT_MAX;
        for (int k = 0; k < 32; ++k) mx = fmaxf(mx, gate[b * 32 + k]);
        float e[32];
        float s = 0.f;
        for (int k = 0; k < 32; ++k) { e[k] = expf(gate[b * 32 + k] - mx); s += e[k]; }
        float inv = 1.f / s;
        for (int k = 0; k < 32; ++k) out_attn[b * 32 + k] = e[k] * inv;
    }
}

extern "C" void kernel_launch(void* const* d_in, const int* in_sizes, int n_in,
                              void* d_out, int out_size, void* d_ws, size_t ws_size,
                              hipStream_t stream) {
    const float* hidden = (const float*)d_in[0];
    const int*   amask  = (const int*)d_in[1];
    const float* w1     = (const float*)d_in[2];
    const float* b1     = (const float*)d_in[3];
    const float* g1     = (const float*)d_in[4];
    const float* beta1  = (const float*)d_in[5];
    const float* w2     = (const float*)d_in[6];
    const float* b2     = (const float*)d_in[7];
    const float* wp     = (const float*)d_in[8];
    const float* bp     = (const float*)d_in[9];
    const float* wg1    = (const float*)d_in[10];
    const float* bg1    = (const float*)d_in[11];
    const float* wg2    = (const float*)d_in[12];
    const float* bg2    = (const float*)d_in[13];
    const float* gout   = (const float*)d_in[14];
    const float* bout   = (const float*)d_in[15];

    float* ws = (float*)d_ws;
    float*     X    = ws + OFF_X;
    _Float16*  ah   = (_Float16*)(ws + OFF_AH);
    _Float16*  al   = (_Float16*)(ws + OFF_AL);
    _Float16*  bh   = (_Float16*)(ws + OFF_BH);
    _Float16*  bl   = (_Float16*)(ws + OFF_BL);
    float*     sc   = ws + OFF_SC;
    float*     ts   = ws + OFF_TS;
    int*       ti   = (int*)(ws + OFF_TI);
    float*     gl   = ws + OFF_GL;
    float*     Embs = ws + OFF_EMB;
    float*     Y    = ws + OFF_Y;

    float* out = (float*)d_out;
    float* out_embeds = out;                   // 8*32*256 = 65536
    float* out_masks  = out + 65536;           // 256
    float* out_attn   = out + 65792;           // 256
    float* out_scores = out + 66048;           // 256
    float* out_spans  = out + 66304;           // 512

    prep_kernel<<<3504, 256, 0, stream>>>(hidden, w1, ah, al, bh, bl);
    mfma_gemm_kernel<<<dim3(32, 36), 256, 0, stream>>>(ah, al, bh, bl, X);
    score_kernel<<<1024, 256, 0, stream>>>(X, amask, b1, g1, beta1, w2, b2, sc);
    topk_kernel<<<8, 256, 0, stream>>>(sc, ts, ti, out_masks, out_scores, out_spans);
    gather_emb_kernel<<<256, 256, 0, stream>>>(hidden, ts, ti, Embs);
    phrase_gemm_kernel<<<dim3(8, 10), 256, 0, stream>>>(Embs, wg1, bg1, wp, bp, Y);
    phrase_post_kernel<<<64, 256, 0, stream>>>(Y, wg2, bg2, ts, gout, bout, gl, out_embeds);
    attn_kernel<<<1, 64, 0, stream>>>(gl, out_attn);
}

// Round 6
// 236.305 us; speedup vs baseline: 2.1388x; 1.1695x over previous
//
#include <hip/hip_runtime.h>
#include <float.h>
#include <math.h>
#include <stdint.h>

#define B_   8
#define L_   512
#define H_   768
#define W_   5
#define K_   32
#define P_   256
#define EPS_ 1e-5f
#define NEG_ -1e30f

typedef _Float16 half8 __attribute__((ext_vector_type(8)));
typedef _Float16 half4v __attribute__((ext_vector_type(4)));
typedef float floatx4 __attribute__((ext_vector_type(4)));

// ---------------- ws layout (float units) ----------------
static const size_t OFF_X   = 0;                   // 4096*2304 f32
static const size_t OFF_AH  = 9437184;             // 4096*768 f16 (hi)
static const size_t OFF_AL  = 11010048;            // 4096*768 f16 (lo)
static const size_t OFF_BH  = 12582912;            // 2304*768 f16 (WtT hi)
static const size_t OFF_BL  = 13467648;            // 2304*768 f16 (WtT lo)
static const size_t OFF_SC  = 14352384;            // 8*2560 scores
static const size_t OFF_TS  = 14372864;            // 256
static const size_t OFF_TI  = 14373120;            // 256 (int)
static const size_t OFF_GL  = 14373376;            // 256
static const size_t OFF_EMB = 14373632;            // 256*768
static const size_t OFF_Y   = 14570240;            // 256*640

#define A_SCALE 8.0f
#define B_SCALE 64.0f
#define INV_SCALE (1.0f / 512.0f)

// ---------------- kernel 1: fused prep: split hidden + build WtT hi/lo ----------------
__global__ __launch_bounds__(256) void prep_kernel(const float* __restrict__ hid,
                                                   const float* __restrict__ w1,
                                                   _Float16* __restrict__ ah,
                                                   _Float16* __restrict__ al,
                                                   _Float16* __restrict__ bh,
                                                   _Float16* __restrict__ bl) {
    __shared__ float ld[64][65];
    if (blockIdx.x < 3072) {
        int idx = (blockIdx.x * 256 + threadIdx.x) * 4;
        float4 x = *(const float4*)(hid + idx);
        float xs[4] = {x.x * A_SCALE, x.y * A_SCALE, x.z * A_SCALE, x.w * A_SCALE};
        half4v h, l;
#pragma unroll
        for (int i = 0; i < 4; ++i) {
            _Float16 hi = (_Float16)xs[i];
            h[i] = hi;
            l[i] = (_Float16)(xs[i] - (float)hi);
        }
        *(half4v*)(ah + idx) = h;
        *(half4v*)(al + idx) = l;
    } else {
        int bid = blockIdx.x - 3072;          // 0..431
        int n0 = (bid / 12) * 64;
        int k0 = (bid % 12) * 64;
        int t = threadIdx.x;
        int rsel = n0 / 768;
        int c0 = n0 - rsel * 768;
#pragma unroll 4
        for (int r = 0; r < 16; ++r) {
            int idx = r * 256 + t;
            int kk = idx >> 6, nn = idx & 63;
            int k = k0 + kk, c = c0 + nn;
            float v;
            if (rsel == 0)      v = w1[(size_t)k * 768 + c] - w1[(size_t)(2304 + k) * 768 + c];
            else if (rsel == 1) v = w1[(size_t)(768 + k) * 768 + c] + w1[(size_t)(2304 + k) * 768 + c];
            else                v = w1[(size_t)(1536 + k) * 768 + c];
            ld[kk][nn] = v * B_SCALE;
        }
        __syncthreads();
#pragma unroll 4
        for (int r = 0; r < 16; ++r) {
            int idx = r * 256 + t;
            int nn = idx >> 6, kk = idx & 63;
            float v = ld[kk][nn];
            _Float16 h = (_Float16)v;
            _Float16 lo = (_Float16)(v - (float)h);
            size_t o = (size_t)(n0 + nn) * 768 + k0 + kk;
            bh[o] = h;
            bl[o] = lo;
        }
    }
}

// ---------------- kernel 2: split-f16 MFMA GEMM, 128x64 tile, LDS double-buffer ------
typedef const __attribute__((address_space(1))) void* gas_ptr;
typedef __attribute__((address_space(3))) void* las_ptr;
__device__ __forceinline__ void async_ld16(const _Float16* g, _Float16* l) {
    __builtin_amdgcn_global_load_lds((gas_ptr)g, (las_ptr)l, 16, 0, 0);
}

__global__ __launch_bounds__(256) void mfma_gemm_kernel(const _Float16* __restrict__ Ah,
                                                        const _Float16* __restrict__ Al,
                                                        const _Float16* __restrict__ Bh,
                                                        const _Float16* __restrict__ Bl,
                                                        float* __restrict__ C) {
    __shared__ _Float16 sAh[2 * 4096];   // [parity][128 rows x 32 k]
    __shared__ _Float16 sAl[2 * 4096];
    __shared__ _Float16 sBh[2 * 2048];   // [parity][64 rows x 32 k]
    __shared__ _Float16 sBl[2 * 2048];
    int tid = threadIdx.x;
    int lane = tid & 63;
    int wave = tid >> 6;
    int m0 = blockIdx.x * 128, n0 = blockIdx.y * 64;

    const _Float16* src = (wave == 0) ? Ah : (wave == 1) ? Al : (wave == 2) ? Bh : Bl;
    _Float16* dstb = (wave == 0) ? sAh : (wave == 1) ? sAl : (wave == 2) ? sBh : sBl;
    int psz  = (wave < 2) ? 4096 : 2048;
    int nch  = (wave < 2) ? 8 : 4;
    int row0 = (wave < 2) ? m0 : n0;
    int qg = (lane & 3) ^ ((lane >> 3) & 3);            // swizzled source k-group
    const _Float16* gp = src + (size_t)(row0 + (lane >> 2)) * 768 + qg * 8;

    int wr = wave >> 1, wc = wave & 1;
    int off_lane = (lane & 15) * 64 + (((lane >> 4) ^ ((lane >> 1) & 3)) * 16);  // bytes
    floatx4 acc[4][2];
#pragma unroll
    for (int i = 0; i < 4; ++i)
#pragma unroll
        for (int j = 0; j < 2; ++j)
            acc[i][j] = (floatx4){0.f, 0.f, 0.f, 0.f};

#pragma unroll
    for (int c = 0; c < 8; ++c) {
        if (c < nch) async_ld16(gp + (size_t)c * 16 * 768, dstb + c * 512);
    }

    int parity = 0;
    for (int k0 = 0; k0 < 768; k0 += 32) {
        __syncthreads();
        if (k0 + 32 < 768) {
            _Float16* dst = dstb + (parity ^ 1) * psz;
            const _Float16* g = gp + k0 + 32;
#pragma unroll
            for (int c = 0; c < 8; ++c) {
                if (c < nch) async_ld16(g + (size_t)c * 16 * 768, dst + c * 512);
            }
        }

        const char* bAh = (const char*)sAh + parity * 8192 + wr * 4096 + off_lane;
        const char* bAl = (const char*)sAl + parity * 8192 + wr * 4096 + off_lane;
        const char* bBh = (const char*)sBh + parity * 4096 + wc * 2048 + off_lane;
        const char* bBl = (const char*)sBl + parity * 4096 + wc * 2048 + off_lane;
        half8 a_h[4], a_l[4], b_h[2], b_l[2];
#pragma unroll
        for (int i = 0; i < 4; ++i) {
            a_h[i] = *(const half8*)(bAh + i * 1024);
            a_l[i] = *(const half8*)(bAl + i * 1024);
        }
#pragma unroll
        for (int j = 0; j < 2; ++j) {
            b_h[j] = *(const half8*)(bBh + j * 1024);
            b_l[j] = *(const half8*)(bBl + j * 1024);
        }
#pragma unroll
        for (int i = 0; i < 4; ++i)
#pragma unroll
            for (int j = 0; j < 2; ++j) {
                acc[i][j] = __builtin_amdgcn_mfma_f32_16x16x32_f16(a_h[i], b_h[j], acc[i][j], 0, 0, 0);
                acc[i][j] = __builtin_amdgcn_mfma_f32_16x16x32_f16(a_h[i], b_l[j], acc[i][j], 0, 0, 0);
                acc[i][j] = __builtin_amdgcn_mfma_f32_16x16x32_f16(a_l[i], b_h[j], acc[i][j], 0, 0, 0);
            }
        parity ^= 1;
    }

    int colc = lane & 15, quad = lane >> 4;
#pragma unroll
    for (int i = 0; i < 4; ++i) {
#pragma unroll
        for (int r = 0; r < 4; ++r) {
            int row = m0 + wr * 64 + i * 16 + quad * 4 + r;
            float* Cp = C + (size_t)row * 2304 + n0 + wc * 32 + colc;
#pragma unroll
            for (int j = 0; j < 2; ++j)
                Cp[j * 16] = acc[i][j][r] * INV_SCALE;
        }
    }
}

// ---------------- kernel 3: per-(b,i) span scores, one wave per (b,i), float4 ---------
__global__ __launch_bounds__(256) void score_kernel(const float* __restrict__ X,
                                                    const int* __restrict__ mask,
                                                    const float* __restrict__ b1,
                                                    const float* __restrict__ g1,
                                                    const float* __restrict__ beta1,
                                                    const float* __restrict__ w2,
                                                    const float* __restrict__ b2,
                                                    float* __restrict__ scores) {
    int wave = threadIdx.x >> 6;
    int lane = threadIdx.x & 63;
    int bi = blockIdx.x * 4 + wave;    // 0..4095
    int b = bi >> 9, i = bi & 511;

    float4 a[3], b1c[3], g1c[3], btc[3], w2c[3], ss[3], e[3];
    const float4* Xrow = (const float4*)(X + (size_t)bi * 2304);
#pragma unroll
    for (int q = 0; q < 3; ++q) {
        int f = lane + q * 64;
        a[q]   = Xrow[f];
        b1c[q] = ((const float4*)b1)[f];
        g1c[q] = ((const float4*)g1)[f];
        btc[q] = ((const float4*)beta1)[f];
        w2c[q] = ((const float4*)w2)[f];
        ss[q]  = make_float4(0.f, 0.f, 0.f, 0.f);
    }
    float bias2 = b2[0];
    int jcur = i - 1;
    float sc_loc[W_];

    for (int w = 0; w < W_; ++w) {
        int j = min(i + w, 511);
        const float4* Xj = (const float4*)(X + (size_t)(b * 512 + j) * 2304);
        if (j > jcur) {
#pragma unroll
            for (int q = 0; q < 3; ++q) {
                int f = lane + q * 64;
                float4 cc = Xj[384 + f];
                ss[q].x += cc.x; ss[q].y += cc.y; ss[q].z += cc.z; ss[q].w += cc.w;
                e[q] = Xj[192 + f];
            }
            jcur = j;
        }
        float invw = 1.0f / (float)(w + 1);
        float4 h[3];
        float psum = 0.f;
#pragma unroll
        for (int q = 0; q < 3; ++q) {
            h[q].x = a[q].x + e[q].x + ss[q].x * invw + b1c[q].x;
            h[q].y = a[q].y + e[q].y + ss[q].y * invw + b1c[q].y;
            h[q].z = a[q].z + e[q].z + ss[q].z * invw + b1c[q].z;
            h[q].w = a[q].w + e[q].w + ss[q].w * invw + b1c[q].w;
            psum += h[q].x + h[q].y + h[q].z + h[q].w;
        }
#pragma unroll
        for (int m = 1; m < 64; m <<= 1) psum += __shfl_xor(psum, m, 64);
        float mean = psum * (1.f / 768.f);

        float pv = 0.f;
#pragma unroll
        for (int q = 0; q < 3; ++q) {
            float dx = h[q].x - mean, dy = h[q].y - mean, dz = h[q].z - mean, dw = h[q].w - mean;
            pv += dx * dx + dy * dy + dz * dz + dw * dw;
        }
#pragma unroll
        for (int m = 1; m < 64; m <<= 1) pv += __shfl_xor(pv, m, 64);
        float rstd = rsqrtf(pv * (1.f / 768.f) + EPS_);

        float pd = 0.f;
#pragma unroll
        for (int q = 0; q < 3; ++q) {
            float yx = fmaxf((h[q].x - mean) * rstd * g1c[q].x + btc[q].x, 0.f);
            float yy = fmaxf((h[q].y - mean) * rstd * g1c[q].y + btc[q].y, 0.f);
            float yz = fmaxf((h[q].z - mean) * rstd * g1c[q].z + btc[q].z, 0.f);
            float yw = fmaxf((h[q].w - mean) * rstd * g1c[q].w + btc[q].w, 0.f);
            pd += yx * w2c[q].x + yy * w2c[q].y + yz * w2c[q].z + yw * w2c[q].w;
        }
#pragma unroll
        for (int m = 1; m < 64; m <<= 1) pd += __shfl_xor(pd, m, 64);
        sc_loc[w] = pd + bias2;
    }

    if (lane < W_) {
        int w = lane;
        bool ok = (i + w) < 512;
        if (ok) {
            for (int t = 0; t <= w; ++t) ok = ok && (mask[b * 512 + i + t] != 0);
        }
        scores[b * 2560 + i * 5 + w] = ok ? sc_loc[w] : NEG_;
    }
}

// ---------------- kernel 4: per-b top-32 via u64 keys + register heads ----------------
// key = (monotone(score_bits) << 32) | (0xFFFFFFFF - idx): u64 max == (value desc, idx asc),
// exactly jax.lax.top_k tie semantics. Each thread sorts its 10 elements once (static
// odd-even transposition network), keeps head in a register; per extraction: wave
// shuffle-max + 4-leader merge; unique winner pops from its LDS spill list.
__device__ __forceinline__ uint64_t shfl_xor_u64(uint64_t x, int m) {
    uint32_t lo = (uint32_t)x, hi = (uint32_t)(x >> 32);
    lo = (uint32_t)__shfl_xor((int)lo, m, 64);
    hi = (uint32_t)__shfl_xor((int)hi, m, 64);
    return ((uint64_t)hi << 32) | lo;
}

__global__ __launch_bounds__(256) void topk_kernel(const float* __restrict__ scores,
                                                   float* __restrict__ tops,
                                                   int* __restrict__ topi,
                                                   float* __restrict__ out_masks,
                                                   float* __restrict__ out_scores,
                                                   float* __restrict__ out_spans) {
    int b = blockIdx.x;
    int tid = threadIdx.x;
    int lane = tid & 63;
    int wv = tid >> 6;
    __shared__ uint64_t lists[256 * 9];
    __shared__ uint64_t wmax[4];
    __shared__ uint64_t gS;

    uint64_t v[10];
#pragma unroll
    for (int q = 0; q < 10; ++q) {
        int t = q * 256 + tid;
        float f = scores[b * 2560 + t];
        uint32_t bits = __float_as_uint(f);
        uint32_t mk = bits ^ ((bits & 0x80000000u) ? 0xFFFFFFFFu : 0x80000000u);
        v[q] = ((uint64_t)mk << 32) | (uint64_t)(0xFFFFFFFFu - (uint32_t)t);
    }
    // odd-even transposition sort, descending, 10 passes (static indices)
#pragma unroll
    for (int p = 0; p < 5; ++p) {
#pragma unroll
        for (int i = 0; i < 9; i += 2) {       // even phase: (0,1)(2,3)(4,5)(6,7)(8,9)
            if (v[i] < v[i + 1]) { uint64_t t = v[i]; v[i] = v[i + 1]; v[i + 1] = t; }
        }
#pragma unroll
        for (int i = 1; i < 9; i += 2) {       // odd phase: (1,2)(3,4)(5,6)(7,8)
            if (v[i] < v[i + 1]) { uint64_t t = v[i]; v[i] = v[i + 1]; v[i + 1] = t; }
        }
    }
#pragma unroll
    for (int j = 0; j < 9; ++j) lists[tid * 9 + j] = v[j + 1];
    uint64_t my = v[0];
    int h = 0;

    for (int k = 0; k < K_; ++k) {
        uint64_t m = my;
#pragma unroll
        for (int s = 1; s < 64; s <<= 1) {
            uint64_t o = shfl_xor_u64(m, s);
            if (o > m) m = o;
        }
        if (lane == 0) wmax[wv] = m;
        __syncthreads();
        if (tid == 0) {
            uint64_t g = wmax[0];
#pragma unroll
            for (int q = 1; q < 4; ++q) if (wmax[q] > g) g = wmax[q];
            gS = g;
            uint32_t mk = (uint32_t)(g >> 32);
            uint32_t bits = mk ^ ((mk & 0x80000000u) ? 0x80000000u : 0xFFFFFFFFu);
            float tv = __uint_as_float(bits);
            int tix = (int)(0xFFFFFFFFu - (uint32_t)(g & 0xFFFFFFFFu));
            tops[b * 32 + k] = tv;
            topi[b * 32 + k] = tix;
            bool mm = tv > (NEG_ * 0.5f);
            out_masks[b * 32 + k] = mm ? 1.0f : 0.0f;
            out_scores[b * 32 + k] = mm ? tv : -10.0f;
            int tI = tix / 5, tw = tix % 5;
            out_spans[(b * 32 + k) * 2 + 0] = mm ? (float)tI : 0.0f;
            out_spans[(b * 32 + k) * 2 + 1] = mm ? (float)(tI + tw) : 0.0f;
        }
        __syncthreads();
        uint64_t g = gS;
        if (my == g) {
            my = (h < 9) ? lists[tid * 9 + h] : 0ull;
            ++h;
        }
    }
}

// ---------------- kernel 5: gather phrase mean-embeddings into Embs[256][768] ---------
__global__ __launch_bounds__(256) void gather_emb_kernel(const float* __restrict__ hidden,
                                                         const float* __restrict__ tops,
                                                         const int* __restrict__ topi,
                                                         float* __restrict__ Embs) {
    int bk = blockIdx.x;            // 0..255
    int b = bk >> 5;
    int tid = threadIdx.x;
    int idx = topi[bk];
    bool valid = tops[bk] > (NEG_ * 0.5f);
    int tI = idx / 5, tw = idx % 5;
    int jend = min(tI + tw, L_ - 1);
    float inv = 1.0f / (float)(tw + 1);
#pragma unroll
    for (int q = 0; q < 3; ++q) {
        int c = tid + q * 256;
        float s = 0.f;
        if (valid) {
            for (int l = tI; l <= jend; ++l) s += hidden[(size_t)(b * 512 + l) * 768 + c];
            s *= inv;
        }
        Embs[(size_t)bk * 768 + c] = s;
    }
}

// ---------------- kernel 6: Y[256][640] = Embs @ [wg1|wp] + [bg1|bp] ----------------
__global__ __launch_bounds__(256) void phrase_gemm_kernel(const float* __restrict__ Embs,
                                                          const float* __restrict__ wg1,
                                                          const float* __restrict__ bg1,
                                                          const float* __restrict__ wp,
                                                          const float* __restrict__ bp,
                                                          float* __restrict__ Y) {
    __shared__ float As[32][34];   // [k][r]
    __shared__ float Bs[32][64];   // [k][c]
    int tid = threadIdx.x;
    int m0 = blockIdx.x * 32;
    int cn0 = blockIdx.y * 64;
    const float* Wp; const float* biasp; int ldw;
    if (cn0 < 384) { Wp = wg1 + cn0;        biasp = bg1 + cn0;        ldw = 384; }
    else           { Wp = wp + (cn0 - 384); biasp = bp + (cn0 - 384); ldw = 256; }

    int tx = tid & 15;       // cols tx*4
    int ty = tid >> 4;       // rows ty*2
    int ar = tid >> 3, akq = (tid & 7) * 4;
    int bk = tid >> 3, bcq = (tid & 7) * 8;
    float acc[2][4] = {};

    for (int k0 = 0; k0 < 768; k0 += 32) {
        float4 av  = *(const float4*)(Embs + (size_t)(m0 + ar) * 768 + k0 + akq);
        float4 bv0 = *(const float4*)(Wp + (size_t)(k0 + bk) * ldw + bcq);
        float4 bv1 = *(const float4*)(Wp + (size_t)(k0 + bk) * ldw + bcq + 4);
        __syncthreads();
        As[akq + 0][ar] = av.x;
        As[akq + 1][ar] = av.y;
        As[akq + 2][ar] = av.z;
        As[akq + 3][ar] = av.w;
        *(float4*)&Bs[bk][bcq]     = bv0;
        *(float4*)&Bs[bk][bcq + 4] = bv1;
        __syncthreads();
#pragma unroll
        for (int kk = 0; kk < 32; ++kk) {
            float2 a = *(const float2*)&As[kk][ty * 2];
            float4 b = *(const float4*)&Bs[kk][tx * 4];
            acc[0][0] += a.x * b.x; acc[0][1] += a.x * b.y; acc[0][2] += a.x * b.z; acc[0][3] += a.x * b.w;
            acc[1][0] += a.y * b.x; acc[1][1] += a.y * b.y; acc[1][2] += a.y * b.z; acc[1][3] += a.y * b.w;
        }
    }
#pragma unroll
    for (int i = 0; i < 2; ++i) {
        float* Yp = Y + (size_t)(m0 + ty * 2 + i) * 640 + cn0 + tx * 4;
        float4 o = make_float4(acc[i][0] + biasp[tx * 4 + 0], acc[i][1] + biasp[tx * 4 + 1],
                               acc[i][2] + biasp[tx * 4 + 2], acc[i][3] + biasp[tx * 4 + 3]);
        *(float4*)Yp = o;
    }
}

// ---------------- kernel 7: per-row gate (tanh . wg2) + LN of projection --------------
__global__ __launch_bounds__(256) void phrase_post_kernel(const float* __restrict__ Y,
                                                          const float* __restrict__ wg2,
                                                          const float* __restrict__ bg2,
                                                          const float* __restrict__ tops,
                                                          const float* __restrict__ gout,
                                                          const float* __restrict__ bout,
                                                          float* __restrict__ gate,
                                                          float* __restrict__ out_embeds) {
    int wv = threadIdx.x >> 6, lane = threadIdx.x & 63;
    int row = blockIdx.x * 4 + wv;   // 64 blocks -> 256 rows
    const float* Yrow = Y + (size_t)row * 640;

    float s = 0.f;
#pragma unroll
    for (int q = 0; q < 6; ++q) {
        int c = lane + q * 64;
        s += tanhf(Yrow[c]) * wg2[c];
    }
#pragma unroll
    for (int m = 1; m < 64; m <<= 1) s += __shfl_xor(s, m, 64);
    if (lane == 0) {
        bool valid = tops[row] > (NEG_ * 0.5f);
        gate[row] = valid ? (s + bg2[0]) : -1e9f;
    }

    float4 p = *(const float4*)(Yrow + 384 + lane * 4);
    float sm = p.x + p.y + p.z + p.w;
#pragma unroll
    for (int m = 1; m < 64; m <<= 1) sm += __shfl_xor(sm, m, 64);
    float mean = sm * (1.f / 256.f);
    float dx = p.x - mean, dy = p.y - mean, dz = p.z - mean, dw = p.w - mean;
    float v = dx * dx + dy * dy + dz * dz + dw * dw;
#pragma unroll
    for (int m = 1; m < 64; m <<= 1) v += __shfl_xor(v, m, 64);
    float rstd = rsqrtf(v * (1.f / 256.f) + EPS_);
    int c = lane * 4;
    float4 o;
    o.x = dx * rstd * gout[c]     + bout[c];
    o.y = dy * rstd * gout[c + 1] + bout[c + 1];
    o.z = dz * rstd * gout[c + 2] + bout[c + 2];
    o.w = dw * rstd * gout[c + 3] + bout[c + 3];
    *(float4*)(out_embeds + (size_t)row * 256 + c) = o;
}

// ---------------- kernel 8: softmax over K per b ----------------
__global__ void attn_kernel(const float* __restrict__ gate, float* __restrict__ out_attn) {
    int b = threadIdx.x;
    if (b < 8) {
        float mx = -FLT_MAX;
        for (int k = 0; k < 32; ++k) mx = fmaxf(mx, gate[b * 32 + k]);
        float e[32];
        float s = 0.f;
        for (int k = 0; k < 32; ++k) { e[k] = expf(gate[b * 32 + k] - mx); s += e[k]; }
        float inv = 1.f / s;
        for (int k = 0; k < 32; ++k) out_attn[b * 32 + k] = e[k] * inv;
    }
}

extern "C" void kernel_launch(void* const* d_in, const int* in_sizes, int n_in,
                              void* d_out, int out_size, void* d_ws, size_t ws_size,
                              hipStream_t stream) {
    const float* hidden = (const float*)d_in[0];
    const int*   amask  = (const int*)d_in[1];
    const float* w1     = (const float*)d_in[2];
    const float* b1     = (const float*)d_in[3];
    const float* g1     = (const float*)d_in[4];
    const float* beta1  = (const float*)d_in[5];
    const float* w2     = (const float*)d_in[6];
    const float* b2     = (const float*)d_in[7];
    const float* wp     = (const float*)d_in[8];
    const float* bp     = (const float*)d_in[9];
    const float* wg1    = (const float*)d_in[10];
    const float* bg1    = (const float*)d_in[11];
    const float* wg2    = (const float*)d_in[12];
    const float* bg2    = (const float*)d_in[13];
    const float* gout   = (const float*)d_in[14];
    const float* bout   = (const float*)d_in[15];

    float* ws = (float*)d_ws;
    float*     X    = ws + OFF_X;
    _Float16*  ah   = (_Float16*)(ws + OFF_AH);
    _Float16*  al   = (_Float16*)(ws + OFF_AL);
    _Float16*  bh   = (_Float16*)(ws + OFF_BH);
    _Float16*  bl   = (_Float16*)(ws + OFF_BL);
    float*     sc   = ws + OFF_SC;
    float*     ts   = ws + OFF_TS;
    int*       ti   = (int*)(ws + OFF_TI);
    float*     gl   = ws + OFF_GL;
    float*     Embs = ws + OFF_EMB;
    float*     Y    = ws + OFF_Y;

    float* out = (float*)d_out;
    float* out_embeds = out;                   // 8*32*256 = 65536
    float* out_masks  = out + 65536;           // 256
    float* out_attn   = out + 65792;           // 256
    float* out_scores = out + 66048;           // 256
    float* out_spans  = out + 66304;           // 512

    prep_kernel<<<3504, 256, 0, stream>>>(hidden, w1, ah, al, bh, bl);
    mfma_gemm_kernel<<<dim3(32, 36), 256, 0, stream>>>(ah, al, bh, bl, X);
    score_kernel<<<1024, 256, 0, stream>>>(X, amask, b1, g1, beta1, w2, b2, sc);
    topk_kernel<<<8, 256, 0, stream>>>(sc, ts, ti, out_masks, out_scores, out_spans);
    gather_emb_kernel<<<256, 256, 0, stream>>>(hidden, ts, ti, Embs);
    phrase_gemm_kernel<<<dim3(8, 10), 256, 0, stream>>>(Embs, wg1, bg1, wp, bp, Y);
    phrase_post_kernel<<<64, 256, 0, stream>>>(Y, wg2, bg2, ts, gout, bout, gl, out_embeds);
    attn_kernel<<<1, 64, 0, stream>>>(gl, out_attn);
}